// Round 1
// baseline (1462.260 us; speedup 1.0000x reference)
//
#include <hip/hip_runtime.h>
#include <hip/hip_bf16.h>

#define G 200
#define NDIM 32
#define EDIM 19
#define KIN 51  // NDIM + EDIM

typedef unsigned short u16;
typedef unsigned int u32;

__device__ __forceinline__ float lrelu(float x){ return x > 0.f ? x : 0.01f*x; }
// sortable-uint encoding for float atomicMax
__device__ __forceinline__ u32 encf(float f){ u32 u = __float_as_uint(f); return (u & 0x80000000u) ? ~u : (u | 0x80000000u); }
__device__ __forceinline__ float decf(u32 u){ return __uint_as_float((u & 0x80000000u) ? (u ^ 0x80000000u) : ~u); }
// bf16 pack (RNE) / unpack
__device__ __forceinline__ u16 f2b(float x){ u32 u = __float_as_uint(x); return (u16)((u + 0x7fffu + ((u >> 16) & 1u)) >> 16); }
__device__ __forceinline__ float b2f(u16 x){ return __uint_as_float(((u32)x) << 16); }

// ---------------- init ----------------
__global__ void init_kernel(u32* __restrict__ m, float* __restrict__ denom, int* __restrict__ deg, int N){
  int i = blockIdx.x * 256 + threadIdx.x;
  if (i < N){ m[i] = 0u; denom[i] = 0.f; deg[i] = 0; }
}

// ---------------- generic tiled GEMM: C = act(A[M,K] @ W[Nout,K]^T + bias) ----------------
// ACT: 0 = none, 1 = leaky_relu, 2 = elu with per-row bias flag (offsets[row+1]>offsets[row])
template<int ACT>
__global__ __launch_bounds__(256) void gemm_kernel(
    const float* __restrict__ A, const float* __restrict__ W, const float* __restrict__ bias,
    const int* __restrict__ offsets, float* __restrict__ C, int M, int K, int Nout)
{
  const int BK = 20;
  __shared__ float As[BK][64];
  __shared__ float Ws[BK][64];
  int tid = threadIdx.x;
  int tx = tid & 15, ty = tid >> 4;
  int m0 = blockIdx.y * 64, n0 = blockIdx.x * 64;
  float acc[4][4] = {};
  int nK = (K + BK - 1) / BK;
  for (int kt = 0; kt < nK; ++kt){
    int k0 = kt * BK;
    for (int idx = tid; idx < 320; idx += 256){
      int r = idx / 5, kq = idx % 5;
      int row = m0 + r, kk = k0 + kq * 4;
      float4 v = make_float4(0.f,0.f,0.f,0.f);
      if (row < M && kk + 3 < K) v = *(const float4*)(A + (long)row * K + kk);
      As[kq*4+0][r] = v.x; As[kq*4+1][r] = v.y; As[kq*4+2][r] = v.z; As[kq*4+3][r] = v.w;
    }
    for (int idx = tid; idx < 320; idx += 256){
      int r = idx / 5, kq = idx % 5;
      int row = n0 + r, kk = k0 + kq * 4;
      float4 v = make_float4(0.f,0.f,0.f,0.f);
      if (row < Nout && kk + 3 < K) v = *(const float4*)(W + (long)row * K + kk);
      Ws[kq*4+0][r] = v.x; Ws[kq*4+1][r] = v.y; Ws[kq*4+2][r] = v.z; Ws[kq*4+3][r] = v.w;
    }
    __syncthreads();
    #pragma unroll
    for (int k = 0; k < BK; ++k){
      float4 av = *(const float4*)&As[k][ty*4];
      float4 bv = *(const float4*)&Ws[k][tx*4];
      float a4[4] = {av.x, av.y, av.z, av.w};
      float b4[4] = {bv.x, bv.y, bv.z, bv.w};
      #pragma unroll
      for (int i = 0; i < 4; ++i)
        #pragma unroll
        for (int j = 0; j < 4; ++j)
          acc[i][j] += a4[i] * b4[j];
    }
    __syncthreads();
  }
  #pragma unroll
  for (int i = 0; i < 4; ++i){
    int row = m0 + ty*4 + i;
    if (row >= M) continue;
    float bf = 1.f;
    if (ACT == 2) bf = (offsets[row+1] > offsets[row]) ? 1.f : 0.f;
    #pragma unroll
    for (int j = 0; j < 4; ++j){
      int col = n0 + tx*4 + j;
      if (col >= Nout) continue;
      float v = acc[i][j] + ((ACT == 2) ? bf * bias[col] : bias[col]);
      if (ACT == 1) v = lrelu(v);
      if (ACT == 2) v = (v > 0.f) ? v : (__expf(v) - 1.f);
      C[(long)row * Nout + col] = v;
    }
  }
}

// ---------------- fused edge projection + logits ----------------
// per block: 16 edges. he1 = lrelu([nf[src], ef] @ We1^T + be1) -> bf16 global + LDS
// logits = lrelu(We2[:200].hv[dst] + We2[200:].he1 + be2)
__global__ __launch_bounds__(256) void edge1_kernel(
    const float* __restrict__ nf, const float* __restrict__ ef,
    const int* __restrict__ src, const int* __restrict__ dst,
    const float* __restrict__ We1, const float* __restrict__ be1,
    const float* __restrict__ We2, const float* __restrict__ be2,
    const float* __restrict__ hv, u16* __restrict__ he1g, float* __restrict__ logits,
    int E)
{
  __shared__ float We1s[G][52];     // padded (51 -> 52, last col zero)
  __shared__ float xs[16][52];
  __shared__ float he1s[16][G];
  __shared__ int srcs[16], dsts[16];
  int tid = threadIdx.x;
  long e0 = (long)blockIdx.x * 16;

  for (int idx = tid; idx < G * KIN; idx += 256)
    We1s[idx / KIN][idx % KIN] = We1[idx];
  if (tid < G) We1s[tid][51] = 0.f;
  if (tid < 16){
    long e = e0 + tid;
    srcs[tid] = (e < E) ? src[e] : 0;
    dsts[tid] = (e < E) ? dst[e] : 0;
  }
  __syncthreads();
  for (int idx = tid; idx < 16 * 52; idx += 256){
    int el = idx / 52, k = idx % 52;
    long e = e0 + el;
    float v = 0.f;
    if (e < E){
      if (k < NDIM) v = nf[(long)srcs[el] * NDIM + k];
      else if (k < KIN) v = ef[e * EDIM + (k - NDIM)];
    }
    xs[el][k] = v;
  }
  __syncthreads();

  int el = tid & 15, q = tid >> 4;
  long e = e0 + el;
  #pragma unroll
  for (int rep = 0; rep < 4; ++rep){
    int g0 = rep * 64 + q * 4;
    if (g0 >= G) continue;
    float a0 = be1[g0], a1 = be1[g0+1], a2 = be1[g0+2], a3 = be1[g0+3];
    #pragma unroll
    for (int kc = 0; kc < 13; ++kc){
      float4 x  = *(const float4*)&xs[el][kc*4];
      float4 w0 = *(const float4*)&We1s[g0+0][kc*4];
      float4 w1 = *(const float4*)&We1s[g0+1][kc*4];
      float4 w2 = *(const float4*)&We1s[g0+2][kc*4];
      float4 w3 = *(const float4*)&We1s[g0+3][kc*4];
      a0 += x.x*w0.x + x.y*w0.y + x.z*w0.z + x.w*w0.w;
      a1 += x.x*w1.x + x.y*w1.y + x.z*w1.z + x.w*w1.w;
      a2 += x.x*w2.x + x.y*w2.y + x.z*w2.z + x.w*w2.w;
      a3 += x.x*w3.x + x.y*w3.y + x.z*w3.z + x.w*w3.w;
    }
    a0 = lrelu(a0); a1 = lrelu(a1); a2 = lrelu(a2); a3 = lrelu(a3);
    he1s[el][g0] = a0; he1s[el][g0+1] = a1; he1s[el][g0+2] = a2; he1s[el][g0+3] = a3;
    if (e < E)
      *(ushort4*)(he1g + e * G + g0) = make_ushort4(f2b(a0), f2b(a1), f2b(a2), f2b(a3));
  }
  __syncthreads();

  int el2 = tid >> 4, j = tid & 15;
  long e2 = e0 + el2;
  int d = dsts[el2];
  float p = 0.f;
  for (int g = j; g < G; g += 16)
    p += We2[g] * hv[(long)d * G + g] + We2[G + g] * he1s[el2][g];
  p += __shfl_down(p, 8, 16);
  p += __shfl_down(p, 4, 16);
  p += __shfl_down(p, 2, 16);
  p += __shfl_down(p, 1, 16);
  if (j == 0 && e2 < E) logits[e2] = lrelu(p + be2[0]);
}

// ---------------- segment max + degree histogram ----------------
__global__ void segmax_kernel(const int* __restrict__ dst, const float* __restrict__ logits,
                              u32* __restrict__ m, int* __restrict__ deg, int E){
  int e = blockIdx.x * 256 + threadIdx.x;
  if (e < E){
    int d = dst[e];
    atomicMax(&m[d], encf(logits[e]));
    atomicAdd(&deg[d], 1);
  }
}

// ---------------- single-block exclusive scan (CSR offsets) ----------------
__global__ __launch_bounds__(1024) void scan_kernel(const int* __restrict__ deg, int* __restrict__ offs,
                                                    int* __restrict__ cur, int N){
  __shared__ int wsums[16];
  __shared__ int carry_s;
  int tid = threadIdx.x;
  int lane = tid & 63, wid = tid >> 6;
  if (tid == 0) carry_s = 0;
  __syncthreads();
  for (int base = 0; base < N; base += 1024){
    int i = base + tid;
    int v = (i < N) ? deg[i] : 0;
    int x = v;
    #pragma unroll
    for (int off = 1; off < 64; off <<= 1){
      int y = __shfl_up(x, off, 64);
      if (lane >= off) x += y;
    }
    if (lane == 63) wsums[wid] = x;
    __syncthreads();
    if (wid == 0){
      int w = (lane < 16) ? wsums[lane] : 0;
      #pragma unroll
      for (int off = 1; off < 16; off <<= 1){
        int y = __shfl_up(w, off, 64);
        if (lane >= off) w += y;
      }
      if (lane < 16) wsums[lane] = w;
    }
    __syncthreads();
    int wexcl = (wid == 0) ? 0 : wsums[wid - 1];
    int incl = carry_s + wexcl + x;
    if (i < N){ offs[i] = incl - v; cur[i] = incl - v; }
    __syncthreads();
    if (tid == 1023) carry_s = incl;
    __syncthreads();
  }
  if (threadIdx.x == 0) offs[N] = carry_s;
}

__global__ void scatter_kernel(const int* __restrict__ dst, int* __restrict__ cur,
                               int* __restrict__ eids, int E){
  int e = blockIdx.x * 256 + threadIdx.x;
  if (e < E){
    int pos = atomicAdd(&cur[dst[e]], 1);
    eids[pos] = e;
  }
}

// ---------------- exp + denom ----------------
__global__ void exsum_kernel(const int* __restrict__ dst, const u32* __restrict__ m,
                             float* __restrict__ lex, float* __restrict__ denom, int E){
  int e = blockIdx.x * 256 + threadIdx.x;
  if (e < E){
    int d = dst[e];
    float ex = __expf(lex[e] - decf(m[d]));
    lex[e] = ex;
    atomicAdd(&denom[d], ex);
  }
}

// ---------------- CSR weighted segment-sum: s[n] = (1/denom) * sum ex_e * he1[e] ----------------
__global__ __launch_bounds__(64) void segsum_kernel(const u16* __restrict__ he1, const float* __restrict__ ex,
    const float* __restrict__ denom, const int* __restrict__ offs, const int* __restrict__ eids,
    float* __restrict__ s, int N)
{
  int n = blockIdx.x;
  if (n >= N) return;
  int l = threadIdx.x;
  if (l >= 50) return;  // 50 lanes x 4 floats = 200
  int beg = offs[n], end = offs[n+1];
  float a0 = 0.f, a1 = 0.f, a2 = 0.f, a3 = 0.f;
  for (int j = beg; j < end; ++j){
    int e = eids[j];
    float w = ex[e];
    ushort4 h = *(const ushort4*)(he1 + (long)e * G + l * 4);
    a0 += w * b2f(h.x); a1 += w * b2f(h.y); a2 += w * b2f(h.z); a3 += w * b2f(h.w);
  }
  float inv = (end > beg) ? 1.0f / denom[n] : 0.f;
  float4 o = make_float4(a0*inv, a1*inv, a2*inv, a3*inv);
  *(float4*)(s + (long)n * G + l * 4) = o;
}

// ---------------- GRU gates + relu ----------------
__device__ __forceinline__ float gruc(float ir, float iz, float inn, float hr, float hz, float hn, float hvv){
  float r = 1.f / (1.f + __expf(-(ir + hr)));
  float z = 1.f / (1.f + __expf(-(iz + hz)));
  float n = tanhf(inn + r * hn);
  float h = (1.f - z) * n + z * hvv;
  return h > 0.f ? h : 0.f;
}

__global__ void gru_kernel(const float* __restrict__ gi, const float* __restrict__ gh,
                           const float* __restrict__ hv, float* __restrict__ out, int N){
  int idx = blockIdx.x * 256 + threadIdx.x;
  if (idx >= N * 50) return;
  int i = idx / 50, g = (idx % 50) * 4;
  const float* gir = gi + (long)i * 600;
  const float* ghr = gh + (long)i * 600;
  float4 ir = *(const float4*)(gir + g);
  float4 iz = *(const float4*)(gir + 200 + g);
  float4 in_ = *(const float4*)(gir + 400 + g);
  float4 hr = *(const float4*)(ghr + g);
  float4 hz = *(const float4*)(ghr + 200 + g);
  float4 hn = *(const float4*)(ghr + 400 + g);
  float4 h = *(const float4*)(hv + (long)i * 200 + g);
  float4 o;
  o.x = gruc(ir.x, iz.x, in_.x, hr.x, hz.x, hn.x, h.x);
  o.y = gruc(ir.y, iz.y, in_.y, hr.y, hz.y, hn.y, h.y);
  o.z = gruc(ir.z, iz.z, in_.z, hr.z, hz.z, hn.z, h.z);
  o.w = gruc(ir.w, iz.w, in_.w, hr.w, hz.w, hn.w, h.w);
  *(float4*)(out + (long)i * 200 + g) = o;
}

extern "C" void kernel_launch(void* const* d_in, const int* in_sizes, int n_in,
                              void* d_out, int out_size, void* d_ws, size_t ws_size,
                              hipStream_t stream)
{
  const float* nf   = (const float*)d_in[0];
  const float* ef   = (const float*)d_in[1];
  const int*   src  = (const int*)d_in[2];
  const int*   dst  = (const int*)d_in[3];
  const float* Wn   = (const float*)d_in[4];
  const float* bn   = (const float*)d_in[5];
  const float* We1  = (const float*)d_in[6];
  const float* be1  = (const float*)d_in[7];
  const float* We2  = (const float*)d_in[8];
  const float* be2  = (const float*)d_in[9];
  const float* Wet  = (const float*)d_in[10];
  const float* bet  = (const float*)d_in[11];
  const float* W_ih = (const float*)d_in[12];
  const float* b_ih = (const float*)d_in[13];
  const float* W_hh = (const float*)d_in[14];
  const float* b_hh = (const float*)d_in[15];
  int N = in_sizes[0] / NDIM;   // 25000
  int E = in_sizes[2];          // 500000
  float* out = (float*)d_out;

  char* p = (char*)d_ws;
  auto alloc = [&](size_t b){ char* r = p; p += (b + 255) & ~(size_t)255; return r; };
  float* hv    = (float*)alloc((size_t)N * G * 4);       // 20 MB
  float* s     = (float*)alloc((size_t)N * G * 4);       // 20 MB
  float* lex   = (float*)alloc((size_t)E * 4);           // logits, then ex (in-place)
  u32*   m     = (u32*)  alloc((size_t)N * 4);
  float* denom = (float*)alloc((size_t)N * 4);
  int*   deg   = (int*)  alloc((size_t)N * 4);
  int*   offs  = (int*)  alloc((size_t)(N + 1) * 4);
  int*   cur   = (int*)  alloc((size_t)N * 4);
  int*   eids  = (int*)  alloc((size_t)E * 4);
  char*  big   = alloc((size_t)E * G * 2);               // 200 MB: he1 (bf16), later context/gi/gh
  u16*   he1   = (u16*)big;
  size_t NG4 = (size_t)N * G * 4;
  float* context = (float*)big;                          // after he1 is dead
  float* gi    = (float*)(big + NG4);
  float* gh    = (float*)(big + NG4 + (size_t)N * 3 * G * 4);

  int eb = (E + 255) / 256;
  int mb = (N + 63) / 64;

  init_kernel<<<dim3((N + 255) / 256), dim3(256), 0, stream>>>(m, denom, deg, N);
  gemm_kernel<1><<<dim3((G + 63) / 64, mb), dim3(256), 0, stream>>>(nf, Wn, bn, nullptr, hv, N, NDIM, G);
  edge1_kernel<<<dim3((E + 15) / 16), dim3(256), 0, stream>>>(nf, ef, src, dst, We1, be1, We2, be2, hv, he1, lex, E);
  segmax_kernel<<<dim3(eb), dim3(256), 0, stream>>>(dst, lex, m, deg, E);
  scan_kernel<<<dim3(1), dim3(1024), 0, stream>>>(deg, offs, cur, N);
  scatter_kernel<<<dim3(eb), dim3(256), 0, stream>>>(dst, cur, eids, E);
  exsum_kernel<<<dim3(eb), dim3(256), 0, stream>>>(dst, m, lex, denom, E);
  segsum_kernel<<<dim3(N), dim3(64), 0, stream>>>(he1, lex, denom, offs, eids, s, N);
  gemm_kernel<2><<<dim3((G + 63) / 64, mb), dim3(256), 0, stream>>>(s, Wet, bet, offs, context, N, G, G);
  gemm_kernel<0><<<dim3((3 * G + 63) / 64, mb), dim3(256), 0, stream>>>(context, W_ih, b_ih, nullptr, gi, N, G, 3 * G);
  gemm_kernel<0><<<dim3((3 * G + 63) / 64, mb), dim3(256), 0, stream>>>(hv, W_hh, b_hh, nullptr, gh, N, G, 3 * G);
  gru_kernel<<<dim3((N * 50 + 255) / 256), dim3(256), 0, stream>>>(gi, gh, hv, out, N);
}

// Round 2
// 834.526 us; speedup vs baseline: 1.7522x; 1.7522x over previous
//
#include <hip/hip_runtime.h>
#include <hip/hip_bf16.h>

#define G 200
#define NDIM 32
#define EDIM 19
#define KIN 51  // NDIM + EDIM

typedef unsigned short u16;
typedef unsigned int u32;

typedef __attribute__((ext_vector_type(8))) short bfrag;   // 8 bf16 (4 VGPRs)
typedef __attribute__((ext_vector_type(4))) float ffrag;   // 4 fp32 acc

__device__ __forceinline__ float lrelu(float x){ return x > 0.f ? x : 0.01f*x; }
// sortable-uint encoding for float atomicMax
__device__ __forceinline__ u32 encf(float f){ u32 u = __float_as_uint(f); return (u & 0x80000000u) ? ~u : (u | 0x80000000u); }
__device__ __forceinline__ float decf(u32 u){ return __uint_as_float((u & 0x80000000u) ? (u ^ 0x80000000u) : ~u); }
// bf16 pack (RNE) / unpack
__device__ __forceinline__ u16 f2b(float x){ u32 u = __float_as_uint(x); return (u16)((u + 0x7fffu + ((u >> 16) & 1u)) >> 16); }
__device__ __forceinline__ float b2f(u16 x){ return __uint_as_float(((u32)x) << 16); }

// ---------------- init ----------------
__global__ void init_kernel(u32* __restrict__ m, float* __restrict__ denom, int* __restrict__ deg, int N){
  int i = blockIdx.x * 256 + threadIdx.x;
  if (i < N){ m[i] = 0u; denom[i] = 0.f; deg[i] = 0; }
}

// ---------------- prep: We1 [200][51] fp32 -> Wbg [208][64] bf16 (zero-padded) ----------------
__global__ void prep_we1_kernel(const float* __restrict__ We1, u16* __restrict__ Wbg){
  int idx = blockIdx.x * 256 + threadIdx.x;
  if (idx < 208 * 64){
    int r = idx >> 6, k = idx & 63;
    float v = (r < G && k < KIN) ? We1[r * KIN + k] : 0.f;
    Wbg[idx] = f2b(v);
  }
}

// ---------------- l1[n] = dot(We2[0:200], hv[n]) ----------------
__global__ __launch_bounds__(256) void l1_kernel(const float* __restrict__ hv, const float* __restrict__ We2,
                                                 float* __restrict__ l1, int N){
  int wv = (blockIdx.x * 256 + threadIdx.x) >> 6;
  int lane = threadIdx.x & 63;
  if (wv >= N) return;
  float p = 0.f;
  for (int g = lane; g < G; g += 64) p += We2[g] * hv[(long)wv * G + g];
  #pragma unroll
  for (int off = 32; off; off >>= 1) p += __shfl_down(p, off, 64);
  if (lane == 0) l1[wv] = p;
}

// ---------------- generic tiled GEMM: C = act(A[M,K] @ W[Nout,K]^T + bias) ----------------
// ACT: 0 = none, 1 = leaky_relu, 2 = elu with per-row bias flag (offsets[row+1]>offsets[row])
template<int ACT>
__global__ __launch_bounds__(256) void gemm_kernel(
    const float* __restrict__ A, const float* __restrict__ W, const float* __restrict__ bias,
    const int* __restrict__ offsets, float* __restrict__ C, int M, int K, int Nout)
{
  const int BK = 20;
  __shared__ float As[BK][64];
  __shared__ float Ws[BK][64];
  int tid = threadIdx.x;
  int tx = tid & 15, ty = tid >> 4;
  int m0 = blockIdx.y * 64, n0 = blockIdx.x * 64;
  float acc[4][4] = {};
  int nK = (K + BK - 1) / BK;
  for (int kt = 0; kt < nK; ++kt){
    int k0 = kt * BK;
    for (int idx = tid; idx < 320; idx += 256){
      int r = idx / 5, kq = idx % 5;
      int row = m0 + r, kk = k0 + kq * 4;
      float4 v = make_float4(0.f,0.f,0.f,0.f);
      if (row < M && kk + 3 < K) v = *(const float4*)(A + (long)row * K + kk);
      As[kq*4+0][r] = v.x; As[kq*4+1][r] = v.y; As[kq*4+2][r] = v.z; As[kq*4+3][r] = v.w;
    }
    for (int idx = tid; idx < 320; idx += 256){
      int r = idx / 5, kq = idx % 5;
      int row = n0 + r, kk = k0 + kq * 4;
      float4 v = make_float4(0.f,0.f,0.f,0.f);
      if (row < Nout && kk + 3 < K) v = *(const float4*)(W + (long)row * K + kk);
      Ws[kq*4+0][r] = v.x; Ws[kq*4+1][r] = v.y; Ws[kq*4+2][r] = v.z; Ws[kq*4+3][r] = v.w;
    }
    __syncthreads();
    #pragma unroll
    for (int k = 0; k < BK; ++k){
      float4 av = *(const float4*)&As[k][ty*4];
      float4 bv = *(const float4*)&Ws[k][tx*4];
      float a4[4] = {av.x, av.y, av.z, av.w};
      float b4[4] = {bv.x, bv.y, bv.z, bv.w};
      #pragma unroll
      for (int i = 0; i < 4; ++i)
        #pragma unroll
        for (int j = 0; j < 4; ++j)
          acc[i][j] += a4[i] * b4[j];
    }
    __syncthreads();
  }
  #pragma unroll
  for (int i = 0; i < 4; ++i){
    int row = m0 + ty*4 + i;
    if (row >= M) continue;
    float bf = 1.f;
    if (ACT == 2) bf = (offsets[row+1] > offsets[row]) ? 1.f : 0.f;
    #pragma unroll
    for (int j = 0; j < 4; ++j){
      int col = n0 + tx*4 + j;
      if (col >= Nout) continue;
      float v = acc[i][j] + ((ACT == 2) ? bf * bias[col] : bias[col]);
      if (ACT == 1) v = lrelu(v);
      if (ACT == 2) v = (v > 0.f) ? v : (__expf(v) - 1.f);
      C[(long)row * Nout + col] = v;
    }
  }
}

// ---------------- MFMA edge kernel: he1 (bf16 out) + fused logits ----------------
// block = 256 threads (4 waves), 64 edges. X = [nf[src] | ef | 0] in bf16 LDS [64][72] (stride-padded).
// We1b staged from pre-converted bf16 global [208][64] -> LDS [208][72].
// Each wave: 16 edges x 13 n-tiles x (K=64 as 2 MFMA). Logit partial fused from D-frags.
__global__ __launch_bounds__(256) void edge_mfma_kernel(
    const float* __restrict__ nf, const float* __restrict__ ef,
    const int* __restrict__ src, const int* __restrict__ dst,
    const u16* __restrict__ Wbg, const float* __restrict__ be1,
    const float* __restrict__ We2, const float* __restrict__ be2,
    const float* __restrict__ l1,
    u16* __restrict__ he1g, float* __restrict__ logits, int E)
{
  __shared__ __align__(16) u16 Wb[208][72];
  __shared__ __align__(16) u16 Xs[64][72];
  __shared__ float bias_s[208];
  __shared__ float w2hi_s[208];
  __shared__ float plds[64];
  __shared__ int srcs[64], dsts[64];

  int tid = threadIdx.x;
  long e0 = (long)blockIdx.x * 64;

  if (tid < 64){
    long e = e0 + tid;
    srcs[tid] = (e < E) ? src[e] : 0;
    dsts[tid] = (e < E) ? dst[e] : 0;
  }
  if (tid < 208){
    bias_s[tid] = (tid < G) ? be1[tid] : 0.f;
    w2hi_s[tid] = (tid < G) ? We2[G + tid] : 0.f;
  }
  // stage We1b: [208][64] global -> [208][72] LDS, 16B chunks
  for (int idx = tid; idx < 208 * 8; idx += 256){
    int r = idx >> 3, c = idx & 7;
    ulonglong2 v = ((const ulonglong2*)Wbg)[idx];
    *(ulonglong2*)&Wb[r][c * 8] = v;
  }
  __syncthreads();  // srcs ready for X fill
  // fill X tile: k<32 from nf[src], k<51 from ef, else 0
  for (int idx = tid; idx < 64 * 64; idx += 256){
    int el = idx >> 6, k = idx & 63;
    long e = e0 + el;
    float v = 0.f;
    if (e < E){
      if (k < NDIM) v = nf[(long)srcs[el] * NDIM + k];
      else if (k < KIN) v = ef[e * EDIM + (k - NDIM)];
    }
    Xs[el][k] = f2b(v);
  }
  __syncthreads();

  int l = tid & 63, w = tid >> 6;
  int quad = l >> 4, col = l & 15;
  int m0 = w * 16;

  bfrag a0 = *(const bfrag*)&Xs[m0 + col][quad * 8];
  bfrag a1 = *(const bfrag*)&Xs[m0 + col][32 + quad * 8];

  ffrag acc[13];
  #pragma unroll
  for (int t = 0; t < 13; ++t){ acc[t].x = 0.f; acc[t].y = 0.f; acc[t].z = 0.f; acc[t].w = 0.f; }
  #pragma unroll
  for (int t = 0; t < 13; ++t){
    bfrag b0 = *(const bfrag*)&Wb[t * 16 + col][quad * 8];
    bfrag b1 = *(const bfrag*)&Wb[t * 16 + col][32 + quad * 8];
    acc[t] = __builtin_amdgcn_mfma_f32_16x16x32_bf16(a0, b0, acc[t], 0, 0, 0);
    acc[t] = __builtin_amdgcn_mfma_f32_16x16x32_bf16(a1, b1, acc[t], 0, 0, 0);
  }

  // epilogue: bias + lrelu -> he1 store (bf16), fused logit partial
  float pl[4] = {0.f, 0.f, 0.f, 0.f};
  #pragma unroll
  for (int t = 0; t < 13; ++t){
    int g = t * 16 + col;
    if (g < G){
      float bv = bias_s[g], wv = w2hi_s[g];
      #pragma unroll
      for (int r = 0; r < 4; ++r){
        int el = m0 + quad * 4 + r;
        long e = e0 + el;
        float v = acc[t][r] + bv;
        v = lrelu(v);
        pl[r] += wv * v;
        if (e < E) he1g[e * G + g] = f2b(v);
      }
    }
  }
  #pragma unroll
  for (int r = 0; r < 4; ++r){
    pl[r] += __shfl_xor(pl[r], 1, 16);
    pl[r] += __shfl_xor(pl[r], 2, 16);
    pl[r] += __shfl_xor(pl[r], 4, 16);
    pl[r] += __shfl_xor(pl[r], 8, 16);
  }
  if (col == 0){
    #pragma unroll
    for (int r = 0; r < 4; ++r) plds[m0 + quad * 4 + r] = pl[r];
  }
  __syncthreads();
  if (tid < 64){
    long e = e0 + tid;
    if (e < E) logits[e] = lrelu(plds[tid] + l1[dsts[tid]] + be2[0]);
  }
}

// ---------------- segment max + degree histogram ----------------
__global__ void segmax_kernel(const int* __restrict__ dst, const float* __restrict__ logits,
                              u32* __restrict__ m, int* __restrict__ deg, int E){
  int e = blockIdx.x * 256 + threadIdx.x;
  if (e < E){
    int d = dst[e];
    atomicMax(&m[d], encf(logits[e]));
    atomicAdd(&deg[d], 1);
  }
}

// ---------------- single-block exclusive scan (CSR offsets) ----------------
__global__ __launch_bounds__(1024) void scan_kernel(const int* __restrict__ deg, int* __restrict__ offs,
                                                    int* __restrict__ cur, int N){
  __shared__ int wsums[16];
  __shared__ int carry_s;
  int tid = threadIdx.x;
  int lane = tid & 63, wid = tid >> 6;
  if (tid == 0) carry_s = 0;
  __syncthreads();
  for (int base = 0; base < N; base += 1024){
    int i = base + tid;
    int v = (i < N) ? deg[i] : 0;
    int x = v;
    #pragma unroll
    for (int off = 1; off < 64; off <<= 1){
      int y = __shfl_up(x, off, 64);
      if (lane >= off) x += y;
    }
    if (lane == 63) wsums[wid] = x;
    __syncthreads();
    if (wid == 0){
      int w = (lane < 16) ? wsums[lane] : 0;
      #pragma unroll
      for (int off = 1; off < 16; off <<= 1){
        int y = __shfl_up(w, off, 64);
        if (lane >= off) w += y;
      }
      if (lane < 16) wsums[lane] = w;
    }
    __syncthreads();
    int wexcl = (wid == 0) ? 0 : wsums[wid - 1];
    int incl = carry_s + wexcl + x;
    if (i < N){ offs[i] = incl - v; cur[i] = incl - v; }
    __syncthreads();
    if (tid == 1023) carry_s = incl;
    __syncthreads();
  }
  if (threadIdx.x == 0) offs[N] = carry_s;
}

__global__ void scatter_kernel(const int* __restrict__ dst, int* __restrict__ cur,
                               int* __restrict__ eids, int E){
  int e = blockIdx.x * 256 + threadIdx.x;
  if (e < E){
    int pos = atomicAdd(&cur[dst[e]], 1);
    eids[pos] = e;
  }
}

// ---------------- exp + denom ----------------
__global__ void exsum_kernel(const int* __restrict__ dst, const u32* __restrict__ m,
                             float* __restrict__ lex, float* __restrict__ denom, int E){
  int e = blockIdx.x * 256 + threadIdx.x;
  if (e < E){
    int d = dst[e];
    float ex = __expf(lex[e] - decf(m[d]));
    lex[e] = ex;
    atomicAdd(&denom[d], ex);
  }
}

// ---------------- CSR weighted segment-sum: s[n] = (1/denom) * sum ex_e * he1[e] ----------------
__global__ __launch_bounds__(64) void segsum_kernel(const u16* __restrict__ he1, const float* __restrict__ ex,
    const float* __restrict__ denom, const int* __restrict__ offs, const int* __restrict__ eids,
    float* __restrict__ s, int N)
{
  int n = blockIdx.x;
  if (n >= N) return;
  int l = threadIdx.x;
  if (l >= 50) return;  // 50 lanes x 4 floats = 200
  int beg = offs[n], end = offs[n+1];
  float a0 = 0.f, a1 = 0.f, a2 = 0.f, a3 = 0.f;
  for (int j = beg; j < end; ++j){
    int e = eids[j];
    float w = ex[e];
    ushort4 h = *(const ushort4*)(he1 + (long)e * G + l * 4);
    a0 += w * b2f(h.x); a1 += w * b2f(h.y); a2 += w * b2f(h.z); a3 += w * b2f(h.w);
  }
  float inv = (end > beg) ? 1.0f / denom[n] : 0.f;
  float4 o = make_float4(a0*inv, a1*inv, a2*inv, a3*inv);
  *(float4*)(s + (long)n * G + l * 4) = o;
}

// ---------------- GRU gates + relu ----------------
__device__ __forceinline__ float gruc(float ir, float iz, float inn, float hr, float hz, float hn, float hvv){
  float r = 1.f / (1.f + __expf(-(ir + hr)));
  float z = 1.f / (1.f + __expf(-(iz + hz)));
  float n = tanhf(inn + r * hn);
  float h = (1.f - z) * n + z * hvv;
  return h > 0.f ? h : 0.f;
}

__global__ void gru_kernel(const float* __restrict__ gi, const float* __restrict__ gh,
                           const float* __restrict__ hv, float* __restrict__ out, int N){
  int idx = blockIdx.x * 256 + threadIdx.x;
  if (idx >= N * 50) return;
  int i = idx / 50, g = (idx % 50) * 4;
  const float* gir = gi + (long)i * 600;
  const float* ghr = gh + (long)i * 600;
  float4 ir = *(const float4*)(gir + g);
  float4 iz = *(const float4*)(gir + 200 + g);
  float4 in_ = *(const float4*)(gir + 400 + g);
  float4 hr = *(const float4*)(ghr + g);
  float4 hz = *(const float4*)(ghr + 200 + g);
  float4 hn = *(const float4*)(ghr + 400 + g);
  float4 h = *(const float4*)(hv + (long)i * 200 + g);
  float4 o;
  o.x = gruc(ir.x, iz.x, in_.x, hr.x, hz.x, hn.x, h.x);
  o.y = gruc(ir.y, iz.y, in_.y, hr.y, hz.y, hn.y, h.y);
  o.z = gruc(ir.z, iz.z, in_.z, hr.z, hz.z, hn.z, h.z);
  o.w = gruc(ir.w, iz.w, in_.w, hr.w, hz.w, hn.w, h.w);
  *(float4*)(out + (long)i * 200 + g) = o;
}

extern "C" void kernel_launch(void* const* d_in, const int* in_sizes, int n_in,
                              void* d_out, int out_size, void* d_ws, size_t ws_size,
                              hipStream_t stream)
{
  const float* nf   = (const float*)d_in[0];
  const float* ef   = (const float*)d_in[1];
  const int*   src  = (const int*)d_in[2];
  const int*   dst  = (const int*)d_in[3];
  const float* Wn   = (const float*)d_in[4];
  const float* bn   = (const float*)d_in[5];
  const float* We1  = (const float*)d_in[6];
  const float* be1  = (const float*)d_in[7];
  const float* We2  = (const float*)d_in[8];
  const float* be2  = (const float*)d_in[9];
  const float* Wet  = (const float*)d_in[10];
  const float* bet  = (const float*)d_in[11];
  const float* W_ih = (const float*)d_in[12];
  const float* b_ih = (const float*)d_in[13];
  const float* W_hh = (const float*)d_in[14];
  const float* b_hh = (const float*)d_in[15];
  int N = in_sizes[0] / NDIM;   // 25000
  int E = in_sizes[2];          // 500000
  float* out = (float*)d_out;

  char* p = (char*)d_ws;
  auto alloc = [&](size_t b){ char* r = p; p += (b + 255) & ~(size_t)255; return r; };
  float* hv    = (float*)alloc((size_t)N * G * 4);       // 20 MB
  float* s     = (float*)alloc((size_t)N * G * 4);       // 20 MB
  float* lex   = (float*)alloc((size_t)E * 4);           // logits, then ex (in-place)
  u32*   m     = (u32*)  alloc((size_t)N * 4);
  float* denom = (float*)alloc((size_t)N * 4);
  int*   deg   = (int*)  alloc((size_t)N * 4);
  int*   offs  = (int*)  alloc((size_t)(N + 1) * 4);
  int*   cur   = (int*)  alloc((size_t)N * 4);
  int*   eids  = (int*)  alloc((size_t)E * 4);
  u16*   Wbg   = (u16*)  alloc((size_t)208 * 64 * 2);    // We1 bf16 padded
  float* l1    = (float*)alloc((size_t)N * 4);
  char*  big   = alloc((size_t)E * G * 2);               // 200 MB: he1 (bf16), later context/gi/gh
  u16*   he1   = (u16*)big;
  size_t NG4 = (size_t)N * G * 4;
  float* context = (float*)big;                          // after he1 is dead
  float* gi    = (float*)(big + NG4);
  float* gh    = (float*)(big + NG4 + (size_t)N * 3 * G * 4);

  int eb = (E + 255) / 256;
  int mb = (N + 63) / 64;

  init_kernel<<<dim3((N + 255) / 256), dim3(256), 0, stream>>>(m, denom, deg, N);
  prep_we1_kernel<<<dim3((208 * 64 + 255) / 256), dim3(256), 0, stream>>>(We1, Wbg);
  gemm_kernel<1><<<dim3((G + 63) / 64, mb), dim3(256), 0, stream>>>(nf, Wn, bn, nullptr, hv, N, NDIM, G);
  l1_kernel<<<dim3((N * 64 + 255) / 256), dim3(256), 0, stream>>>(hv, We2, l1, N);
  edge_mfma_kernel<<<dim3((E + 63) / 64), dim3(256), 0, stream>>>(nf, ef, src, dst, Wbg, be1, We2, be2, l1, he1, lex, E);
  segmax_kernel<<<dim3(eb), dim3(256), 0, stream>>>(dst, lex, m, deg, E);
  scan_kernel<<<dim3(1), dim3(1024), 0, stream>>>(deg, offs, cur, N);
  scatter_kernel<<<dim3(eb), dim3(256), 0, stream>>>(dst, cur, eids, E);
  exsum_kernel<<<dim3(eb), dim3(256), 0, stream>>>(dst, m, lex, denom, E);
  segsum_kernel<<<dim3(N), dim3(64), 0, stream>>>(he1, lex, denom, offs, eids, s, N);
  gemm_kernel<2><<<dim3((G + 63) / 64, mb), dim3(256), 0, stream>>>(s, Wet, bet, offs, context, N, G, G);
  gemm_kernel<0><<<dim3((3 * G + 63) / 64, mb), dim3(256), 0, stream>>>(context, W_ih, b_ih, nullptr, gi, N, G, 3 * G);
  gemm_kernel<0><<<dim3((3 * G + 63) / 64, mb), dim3(256), 0, stream>>>(hv, W_hh, b_hh, nullptr, gh, N, G, 3 * G);
  gru_kernel<<<dim3((N * 50 + 255) / 256), dim3(256), 0, stream>>>(gi, gh, hv, out, N);
}

// Round 3
// 687.991 us; speedup vs baseline: 2.1254x; 1.2130x over previous
//
#include <hip/hip_runtime.h>
#include <hip/hip_bf16.h>

#define G 200
#define NDIM 32
#define EDIM 19
#define KIN 51  // NDIM + EDIM

typedef unsigned short u16;
typedef unsigned int u32;

typedef __attribute__((ext_vector_type(8))) short bfrag;   // 8 bf16 (4 VGPRs)
typedef __attribute__((ext_vector_type(4))) float ffrag;   // 4 fp32 acc

__device__ __forceinline__ float lrelu(float x){ return x > 0.f ? x : 0.01f*x; }
// bf16 pack (RNE) / unpack
__device__ __forceinline__ u16 f2b(float x){ u32 u = __float_as_uint(x); return (u16)((u + 0x7fffu + ((u >> 16) & 1u)) >> 16); }
__device__ __forceinline__ float b2f(u16 x){ return __uint_as_float(((u32)x) << 16); }

// ---------------- init ----------------
__global__ void init_kernel(float* __restrict__ denom, int* __restrict__ deg, int N){
  int i = blockIdx.x * 256 + threadIdx.x;
  if (i < N){ denom[i] = 0.f; deg[i] = 0; }
}

// ---------------- prep: We1 [200][51] fp32 -> Wbg [208][64] bf16 (zero-padded) ----------------
__global__ void prep_we1_kernel(const float* __restrict__ We1, u16* __restrict__ Wbg){
  int idx = blockIdx.x * 256 + threadIdx.x;
  if (idx < 208 * 64){
    int r = idx >> 6, k = idx & 63;
    float v = (r < G && k < KIN) ? We1[r * KIN + k] : 0.f;
    Wbg[idx] = f2b(v);
  }
}

// ---------------- generic weight prep: W [Nr][Kc] fp32 -> Wb [Npad][Kpad] bf16 ----------------
__global__ void prep_w_kernel(const float* __restrict__ W, u16* __restrict__ Wb,
                              int Nr, int Kc, int Npad, int Kpad){
  int idx = blockIdx.x * 256 + threadIdx.x;
  if (idx < Npad * Kpad){
    int r = idx / Kpad, k = idx % Kpad;
    float v = (r < Nr && k < Kc) ? W[r * Kc + k] : 0.f;
    Wb[idx] = f2b(v);
  }
}

// ---------------- l1[n] = dot(We2[0:200], hv[n]) ----------------
__global__ __launch_bounds__(256) void l1_kernel(const float* __restrict__ hv, const float* __restrict__ We2,
                                                 float* __restrict__ l1, int N){
  int wv = (blockIdx.x * 256 + threadIdx.x) >> 6;
  int lane = threadIdx.x & 63;
  if (wv >= N) return;
  float p = 0.f;
  for (int g = lane; g < G; g += 64) p += We2[g] * hv[(long)wv * G + g];
  #pragma unroll
  for (int off = 32; off; off >>= 1) p += __shfl_down(p, off, 64);
  if (lane == 0) l1[wv] = p;
}

// ---------------- MFMA node GEMM: C = act(A[M,K] @ W^T + bias), W pre-padded bf16 [Npad][Kpad] ----------------
// ACT: 0 = none, 1 = leaky_relu, 2 = elu with per-row bias flag (offsets[row+1]>offsets[row])
// block = 256 (4 waves). Tile: 64 rows x 64 cols. K-loop in chunks of 64 (Kpad % 64 == 0).
template<int ACT>
__global__ __launch_bounds__(256) void mgemm_kernel(
    const float* __restrict__ A, const u16* __restrict__ Wb, const float* __restrict__ bias,
    const int* __restrict__ offsets, float* __restrict__ C, int M, int K, int Nout, int Kpad)
{
  __shared__ __align__(16) u16 As[64][72];
  __shared__ __align__(16) u16 Ws[64][72];
  int tid = threadIdx.x;
  int m0 = blockIdx.y * 64, n0 = blockIdx.x * 64;
  int l = tid & 63, w = tid >> 6, quad = l >> 4, col = l & 15;

  ffrag acc[4];
  #pragma unroll
  for (int t = 0; t < 4; ++t){ acc[t].x = 0.f; acc[t].y = 0.f; acc[t].z = 0.f; acc[t].w = 0.f; }

  int nK = Kpad >> 6;
  for (int kc = 0; kc < nK; ++kc){
    int k0 = kc << 6;
    for (int idx = tid; idx < 64 * 64; idx += 256){
      int r = idx >> 6, k = idx & 63;
      int row = m0 + r;
      float v = (row < M && (k0 + k) < K) ? A[(long)row * K + k0 + k] : 0.f;
      As[r][k] = f2b(v);
    }
    for (int idx = tid; idx < 64 * 8; idx += 256){
      int r = idx >> 3, c = idx & 7;
      *(ulonglong2*)&Ws[r][c * 8] = *(const ulonglong2*)(Wb + (long)(n0 + r) * Kpad + k0 + c * 8);
    }
    __syncthreads();
    bfrag a0 = *(const bfrag*)&As[w * 16 + col][quad * 8];
    bfrag a1 = *(const bfrag*)&As[w * 16 + col][32 + quad * 8];
    #pragma unroll
    for (int t = 0; t < 4; ++t){
      bfrag b0 = *(const bfrag*)&Ws[t * 16 + col][quad * 8];
      bfrag b1 = *(const bfrag*)&Ws[t * 16 + col][32 + quad * 8];
      acc[t] = __builtin_amdgcn_mfma_f32_16x16x32_bf16(a0, b0, acc[t], 0, 0, 0);
      acc[t] = __builtin_amdgcn_mfma_f32_16x16x32_bf16(a1, b1, acc[t], 0, 0, 0);
    }
    __syncthreads();
  }

  #pragma unroll
  for (int t = 0; t < 4; ++t){
    int n = n0 + t * 16 + col;
    if (n >= Nout) continue;
    float bv = bias[n];
    #pragma unroll
    for (int r = 0; r < 4; ++r){
      int row = m0 + w * 16 + quad * 4 + r;
      if (row >= M) continue;
      float v;
      if (ACT == 2){
        float bf = (offsets[row + 1] > offsets[row]) ? 1.f : 0.f;
        v = acc[t][r] + bf * bv;
        v = (v > 0.f) ? v : (__expf(v) - 1.f);
      } else {
        v = acc[t][r] + bv;
        if (ACT == 1) v = lrelu(v);
      }
      C[(long)row * Nout + n] = v;
    }
  }
}

// ---------------- MFMA edge kernel: he1 (bf16 out) + fused logits + deg histogram ----------------
// block = 256 threads (4 waves), 64 edges. X = [nf[src] | ef | 0] in bf16 LDS [64][72].
// After MFMA, Wb LDS is reused as he1 staging [64][208] for coalesced 16B global stores.
__global__ __launch_bounds__(256) void edge_mfma_kernel(
    const float* __restrict__ nf, const float* __restrict__ ef,
    const int* __restrict__ src, const int* __restrict__ dst,
    const u16* __restrict__ Wbg, const float* __restrict__ be1,
    const float* __restrict__ We2, const float* __restrict__ be2,
    const float* __restrict__ l1,
    u16* __restrict__ he1g, float* __restrict__ logits, int* __restrict__ deg, int E)
{
  __shared__ __align__(16) u16 Wb[208][72];   // reused as he1s[64][208] after MFMA
  __shared__ __align__(16) u16 Xs[64][72];
  __shared__ float bias_s[208];
  __shared__ float w2hi_s[208];
  __shared__ float plds[64];
  __shared__ int srcs[64], dsts[64];

  int tid = threadIdx.x;
  long e0 = (long)blockIdx.x * 64;

  if (tid < 64){
    long e = e0 + tid;
    srcs[tid] = (e < E) ? src[e] : 0;
    dsts[tid] = (e < E) ? dst[e] : 0;
  }
  if (tid < 208){
    bias_s[tid] = (tid < G) ? be1[tid] : 0.f;
    w2hi_s[tid] = (tid < G) ? We2[G + tid] : 0.f;
  }
  for (int idx = tid; idx < 208 * 8; idx += 256){
    int r = idx >> 3, c = idx & 7;
    ulonglong2 v = ((const ulonglong2*)Wbg)[idx];
    *(ulonglong2*)&Wb[r][c * 8] = v;
  }
  __syncthreads();  // srcs ready for X fill
  for (int idx = tid; idx < 64 * 64; idx += 256){
    int el = idx >> 6, k = idx & 63;
    long e = e0 + el;
    float v = 0.f;
    if (e < E){
      if (k < NDIM) v = nf[(long)srcs[el] * NDIM + k];
      else if (k < KIN) v = ef[e * EDIM + (k - NDIM)];
    }
    Xs[el][k] = f2b(v);
  }
  __syncthreads();

  int l = tid & 63, w = tid >> 6;
  int quad = l >> 4, col = l & 15;
  int m0 = w * 16;

  bfrag a0 = *(const bfrag*)&Xs[m0 + col][quad * 8];
  bfrag a1 = *(const bfrag*)&Xs[m0 + col][32 + quad * 8];

  ffrag acc[13];
  #pragma unroll
  for (int t = 0; t < 13; ++t){ acc[t].x = 0.f; acc[t].y = 0.f; acc[t].z = 0.f; acc[t].w = 0.f; }
  #pragma unroll
  for (int t = 0; t < 13; ++t){
    bfrag b0 = *(const bfrag*)&Wb[t * 16 + col][quad * 8];
    bfrag b1 = *(const bfrag*)&Wb[t * 16 + col][32 + quad * 8];
    acc[t] = __builtin_amdgcn_mfma_f32_16x16x32_bf16(a0, b0, acc[t], 0, 0, 0);
    acc[t] = __builtin_amdgcn_mfma_f32_16x16x32_bf16(a1, b1, acc[t], 0, 0, 0);
  }
  __syncthreads();  // all Wb reads done; safe to reuse as he1 staging

  u16* he1s = (u16*)&Wb[0][0];  // [64][208]
  float pl[4] = {0.f, 0.f, 0.f, 0.f};
  #pragma unroll
  for (int t = 0; t < 13; ++t){
    int g = t * 16 + col;  // g in [0,208); cols >=200 are zero-weight junk (harmless)
    float bv = bias_s[g], wv = w2hi_s[g];
    #pragma unroll
    for (int r = 0; r < 4; ++r){
      int el = m0 + quad * 4 + r;
      float v = acc[t][r] + bv;
      v = lrelu(v);
      pl[r] += wv * v;
      he1s[el * 208 + g] = f2b(v);
    }
  }
  #pragma unroll
  for (int r = 0; r < 4; ++r){
    pl[r] += __shfl_xor(pl[r], 1, 16);
    pl[r] += __shfl_xor(pl[r], 2, 16);
    pl[r] += __shfl_xor(pl[r], 4, 16);
    pl[r] += __shfl_xor(pl[r], 8, 16);
  }
  if (col == 0){
    #pragma unroll
    for (int r = 0; r < 4; ++r) plds[m0 + quad * 4 + r] = pl[r];
  }
  __syncthreads();
  // coalesced he1 copy-out: 64 edges x 25 ushort8 chunks
  for (int idx = tid; idx < 1600; idx += 256){
    int el = idx / 25, c = idx - el * 25;
    long e = e0 + el;
    if (e < E)
      *(ulonglong2*)(he1g + e * G + c * 8) = *(const ulonglong2*)&he1s[el * 208 + c * 8];
  }
  if (tid < 64){
    long e = e0 + tid;
    if (e < E){
      logits[e] = lrelu(plds[tid] + l1[dsts[tid]] + be2[0]);
      atomicAdd(&deg[dsts[tid]], 1);
    }
  }
}

// ---------------- single-block exclusive scan (CSR offsets) ----------------
__global__ __launch_bounds__(1024) void scan_kernel(const int* __restrict__ deg, int* __restrict__ offs,
                                                    int* __restrict__ cur, int N){
  __shared__ int wsums[16];
  __shared__ int carry_s;
  int tid = threadIdx.x;
  int lane = tid & 63, wid = tid >> 6;
  if (tid == 0) carry_s = 0;
  __syncthreads();
  for (int base = 0; base < N; base += 1024){
    int i = base + tid;
    int v = (i < N) ? deg[i] : 0;
    int x = v;
    #pragma unroll
    for (int off = 1; off < 64; off <<= 1){
      int y = __shfl_up(x, off, 64);
      if (lane >= off) x += y;
    }
    if (lane == 63) wsums[wid] = x;
    __syncthreads();
    if (wid == 0){
      int w = (lane < 16) ? wsums[lane] : 0;
      #pragma unroll
      for (int off = 1; off < 16; off <<= 1){
        int y = __shfl_up(w, off, 64);
        if (lane >= off) w += y;
      }
      if (lane < 16) wsums[lane] = w;
    }
    __syncthreads();
    int wexcl = (wid == 0) ? 0 : wsums[wid - 1];
    int incl = carry_s + wexcl + x;
    if (i < N){ offs[i] = incl - v; cur[i] = incl - v; }
    __syncthreads();
    if (tid == 1023) carry_s = incl;
    __syncthreads();
  }
  if (threadIdx.x == 0) offs[N] = carry_s;
}

// ---------------- scatter + exp + denom (no max subtraction: logits bounded) ----------------
__global__ void scatter_exp_kernel(const int* __restrict__ dst, int* __restrict__ cur,
                                   int* __restrict__ eids, float* __restrict__ lex,
                                   float* __restrict__ denom, int E){
  int e = blockIdx.x * 256 + threadIdx.x;
  if (e < E){
    int d = dst[e];
    int pos = atomicAdd(&cur[d], 1);
    eids[pos] = e;
    float ex = __expf(lex[e]);
    lex[e] = ex;
    atomicAdd(&denom[d], ex);
  }
}

// ---------------- CSR weighted segment-sum: s[n] = (1/denom) * sum ex_e * he1[e] ----------------
__global__ __launch_bounds__(64) void segsum_kernel(const u16* __restrict__ he1, const float* __restrict__ ex,
    const float* __restrict__ denom, const int* __restrict__ offs, const int* __restrict__ eids,
    float* __restrict__ s, int N)
{
  int n = blockIdx.x;
  if (n >= N) return;
  int l = threadIdx.x;
  if (l >= 50) return;  // 50 lanes x 4 floats = 200
  int beg = offs[n], end = offs[n+1];
  float a0 = 0.f, a1 = 0.f, a2 = 0.f, a3 = 0.f;
  int j = beg;
  for (; j + 1 < end; j += 2){
    int ea = eids[j], eb = eids[j + 1];
    float wa = ex[ea], wb = ex[eb];
    ushort4 ha = *(const ushort4*)(he1 + (long)ea * G + l * 4);
    ushort4 hb = *(const ushort4*)(he1 + (long)eb * G + l * 4);
    a0 += wa * b2f(ha.x) + wb * b2f(hb.x);
    a1 += wa * b2f(ha.y) + wb * b2f(hb.y);
    a2 += wa * b2f(ha.z) + wb * b2f(hb.z);
    a3 += wa * b2f(ha.w) + wb * b2f(hb.w);
  }
  if (j < end){
    int ea = eids[j];
    float wa = ex[ea];
    ushort4 ha = *(const ushort4*)(he1 + (long)ea * G + l * 4);
    a0 += wa * b2f(ha.x); a1 += wa * b2f(ha.y); a2 += wa * b2f(ha.z); a3 += wa * b2f(ha.w);
  }
  float inv = (end > beg) ? 1.0f / denom[n] : 0.f;
  float4 o = make_float4(a0*inv, a1*inv, a2*inv, a3*inv);
  *(float4*)(s + (long)n * G + l * 4) = o;
}

// ---------------- GRU gates + relu ----------------
__device__ __forceinline__ float gruc(float ir, float iz, float inn, float hr, float hz, float hn, float hvv){
  float r = 1.f / (1.f + __expf(-(ir + hr)));
  float z = 1.f / (1.f + __expf(-(iz + hz)));
  float n = tanhf(inn + r * hn);
  float h = (1.f - z) * n + z * hvv;
  return h > 0.f ? h : 0.f;
}

__global__ void gru_kernel(const float* __restrict__ gi, const float* __restrict__ gh,
                           const float* __restrict__ hv, float* __restrict__ out, int N){
  int idx = blockIdx.x * 256 + threadIdx.x;
  if (idx >= N * 50) return;
  int i = idx / 50, g = (idx % 50) * 4;
  const float* gir = gi + (long)i * 600;
  const float* ghr = gh + (long)i * 600;
  float4 ir = *(const float4*)(gir + g);
  float4 iz = *(const float4*)(gir + 200 + g);
  float4 in_ = *(const float4*)(gir + 400 + g);
  float4 hr = *(const float4*)(ghr + g);
  float4 hz = *(const float4*)(ghr + 200 + g);
  float4 hn = *(const float4*)(ghr + 400 + g);
  float4 h = *(const float4*)(hv + (long)i * 200 + g);
  float4 o;
  o.x = gruc(ir.x, iz.x, in_.x, hr.x, hz.x, hn.x, h.x);
  o.y = gruc(ir.y, iz.y, in_.y, hr.y, hz.y, hn.y, h.y);
  o.z = gruc(ir.z, iz.z, in_.z, hr.z, hz.z, hn.z, h.z);
  o.w = gruc(ir.w, iz.w, in_.w, hr.w, hz.w, hn.w, h.w);
  *(float4*)(out + (long)i * 200 + g) = o;
}

extern "C" void kernel_launch(void* const* d_in, const int* in_sizes, int n_in,
                              void* d_out, int out_size, void* d_ws, size_t ws_size,
                              hipStream_t stream)
{
  const float* nf   = (const float*)d_in[0];
  const float* ef   = (const float*)d_in[1];
  const int*   src  = (const int*)d_in[2];
  const int*   dst  = (const int*)d_in[3];
  const float* Wn   = (const float*)d_in[4];
  const float* bn   = (const float*)d_in[5];
  const float* We1  = (const float*)d_in[6];
  const float* be1  = (const float*)d_in[7];
  const float* We2  = (const float*)d_in[8];
  const float* be2  = (const float*)d_in[9];
  const float* Wet  = (const float*)d_in[10];
  const float* bet  = (const float*)d_in[11];
  const float* W_ih = (const float*)d_in[12];
  const float* b_ih = (const float*)d_in[13];
  const float* W_hh = (const float*)d_in[14];
  const float* b_hh = (const float*)d_in[15];
  int N = in_sizes[0] / NDIM;   // 25000
  int E = in_sizes[2];          // 500000
  float* out = (float*)d_out;

  char* p = (char*)d_ws;
  auto alloc = [&](size_t b){ char* r = p; p += (b + 255) & ~(size_t)255; return r; };
  float* hv    = (float*)alloc((size_t)N * G * 4);       // 20 MB
  float* s     = (float*)alloc((size_t)N * G * 4);       // 20 MB
  float* lex   = (float*)alloc((size_t)E * 4);           // logits, then ex (in-place)
  float* denom = (float*)alloc((size_t)N * 4);
  int*   deg   = (int*)  alloc((size_t)N * 4);
  int*   offs  = (int*)  alloc((size_t)(N + 1) * 4);
  int*   cur   = (int*)  alloc((size_t)N * 4);
  int*   eids  = (int*)  alloc((size_t)E * 4);
  u16*   Wbg   = (u16*)  alloc((size_t)208 * 64 * 2);    // We1 bf16 padded
  float* l1    = (float*)alloc((size_t)N * 4);
  u16*   Wnb   = (u16*)  alloc((size_t)256 * 64 * 2);
  u16*   Wetb  = (u16*)  alloc((size_t)256 * 256 * 2);
  u16*   Wihb  = (u16*)  alloc((size_t)640 * 256 * 2);
  u16*   Whhb  = (u16*)  alloc((size_t)640 * 256 * 2);
  char*  big   = alloc((size_t)E * G * 2);               // 200 MB: he1 (bf16), later context/gi/gh
  u16*   he1   = (u16*)big;
  size_t NG4 = (size_t)N * G * 4;
  float* context = (float*)big;                          // after he1 is dead
  float* gi    = (float*)(big + NG4);
  float* gh    = (float*)(big + NG4 + (size_t)N * 3 * G * 4);

  int eb = (E + 255) / 256;
  int mb = (N + 63) / 64;

  init_kernel<<<dim3((N + 255) / 256), dim3(256), 0, stream>>>(denom, deg, N);
  prep_we1_kernel<<<dim3((208 * 64 + 255) / 256), dim3(256), 0, stream>>>(We1, Wbg);
  prep_w_kernel<<<dim3((256 * 64 + 255) / 256), dim3(256), 0, stream>>>(Wn, Wnb, G, NDIM, 256, 64);
  prep_w_kernel<<<dim3((256 * 256 + 255) / 256), dim3(256), 0, stream>>>(Wet, Wetb, G, G, 256, 256);
  prep_w_kernel<<<dim3((640 * 256 + 255) / 256), dim3(256), 0, stream>>>(W_ih, Wihb, 3 * G, G, 640, 256);
  prep_w_kernel<<<dim3((640 * 256 + 255) / 256), dim3(256), 0, stream>>>(W_hh, Whhb, 3 * G, G, 640, 256);

  // hv = lrelu(nf @ Wn^T + bn)
  mgemm_kernel<1><<<dim3(4, mb), dim3(256), 0, stream>>>(nf, Wnb, bn, nullptr, hv, N, NDIM, G, 64);
  l1_kernel<<<dim3((N * 64 + 255) / 256), dim3(256), 0, stream>>>(hv, We2, l1, N);
  edge_mfma_kernel<<<dim3((E + 63) / 64), dim3(256), 0, stream>>>(nf, ef, src, dst, Wbg, be1, We2, be2, l1, he1, lex, deg, E);
  scan_kernel<<<dim3(1), dim3(1024), 0, stream>>>(deg, offs, cur, N);
  scatter_exp_kernel<<<dim3(eb), dim3(256), 0, stream>>>(dst, cur, eids, lex, denom, E);
  segsum_kernel<<<dim3(N), dim3(64), 0, stream>>>(he1, lex, denom, offs, eids, s, N);
  // context = elu(s @ Wet^T + bet[nonempty])
  mgemm_kernel<2><<<dim3(4, mb), dim3(256), 0, stream>>>(s, Wetb, bet, offs, context, N, G, G, 256);
  mgemm_kernel<0><<<dim3(10, mb), dim3(256), 0, stream>>>(context, Wihb, b_ih, nullptr, gi, N, G, 3 * G, 256);
  mgemm_kernel<0><<<dim3(10, mb), dim3(256), 0, stream>>>(hv, Whhb, b_hh, nullptr, gh, N, G, 3 * G, 256);
  gru_kernel<<<dim3((N * 50 + 255) / 256), dim3(256), 0, stream>>>(gi, gh, hv, out, N);
}

// Round 4
// 671.105 us; speedup vs baseline: 2.1789x; 1.0252x over previous
//
#include <hip/hip_runtime.h>
#include <hip/hip_bf16.h>

#define G 200
#define NDIM 32
#define EDIM 19
#define KIN 51  // NDIM + EDIM

typedef unsigned short u16;
typedef unsigned int u32;

typedef __attribute__((ext_vector_type(8))) short bfrag;   // 8 bf16 (4 VGPRs)
typedef __attribute__((ext_vector_type(4))) float ffrag;   // 4 fp32 acc

__device__ __forceinline__ float lrelu(float x){ return x > 0.f ? x : 0.01f*x; }
// bf16 pack (RNE) / unpack
__device__ __forceinline__ u16 f2b(float x){ u32 u = __float_as_uint(x); return (u16)((u + 0x7fffu + ((u >> 16) & 1u)) >> 16); }
__device__ __forceinline__ float b2f(u16 x){ return __uint_as_float(((u32)x) << 16); }

// ---------------- init ----------------
__global__ void init_kernel(float* __restrict__ denom, int* __restrict__ deg, int N){
  int i = blockIdx.x * 256 + threadIdx.x;
  if (i < N){ denom[i] = 0.f; deg[i] = 0; }
}

// ---------------- generic weight prep: W [Nr][Kc] fp32 -> Wb [Npad][Kpad] bf16 ----------------
__global__ void prep_w_kernel(const float* __restrict__ W, u16* __restrict__ Wb,
                              int Nr, int Kc, int Npad, int Kpad){
  int idx = blockIdx.x * 256 + threadIdx.x;
  if (idx < Npad * Kpad){
    int r = idx / Kpad, k = idx % Kpad;
    float v = (r < Nr && k < Kc) ? W[r * Kc + k] : 0.f;
    Wb[idx] = f2b(v);
  }
}

// ---------------- l1[n] = dot(We2[0:200], hv[n]) ----------------
__global__ __launch_bounds__(256) void l1_kernel(const float* __restrict__ hv, const float* __restrict__ We2,
                                                 float* __restrict__ l1, int N){
  int wv = (blockIdx.x * 256 + threadIdx.x) >> 6;
  int lane = threadIdx.x & 63;
  if (wv >= N) return;
  float p = 0.f;
  for (int g = lane; g < G; g += 64) p += We2[g] * hv[(long)wv * G + g];
  #pragma unroll
  for (int off = 32; off; off >>= 1) p += __shfl_down(p, off, 64);
  if (lane == 0) l1[wv] = p;
}

// ---------------- MFMA node GEMM: C = act(A[M,K] @ W^T + bias), W pre-padded bf16 [Npad][Kpad] ----------------
// ACT: 0 = none, 1 = leaky_relu, 2 = elu with per-row bias flag (offsets[row+1]>offsets[row])
// Requires K % 4 == 0.
template<int ACT>
__global__ __launch_bounds__(256) void mgemm_kernel(
    const float* __restrict__ A, const u16* __restrict__ Wb, const float* __restrict__ bias,
    const int* __restrict__ offsets, float* __restrict__ C, int M, int K, int Nout, int Kpad)
{
  __shared__ __align__(16) u16 As[64][72];
  __shared__ __align__(16) u16 Ws[64][72];
  int tid = threadIdx.x;
  int m0 = blockIdx.y * 64, n0 = blockIdx.x * 64;
  int l = tid & 63, w = tid >> 6, quad = l >> 4, col = l & 15;

  ffrag acc[4];
  #pragma unroll
  for (int t = 0; t < 4; ++t){ acc[t].x = 0.f; acc[t].y = 0.f; acc[t].z = 0.f; acc[t].w = 0.f; }

  int nK = Kpad >> 6;
  for (int kc = 0; kc < nK; ++kc){
    int k0 = kc << 6;
    for (int idx = tid; idx < 64 * 16; idx += 256){
      int r = idx >> 4, c4 = idx & 15;
      int row = m0 + r, k = k0 + c4 * 4;
      float4 v = make_float4(0.f,0.f,0.f,0.f);
      if (row < M && k < K) v = *(const float4*)(A + (long)row * K + k);
      *(ushort4*)&As[r][c4 * 4] = make_ushort4(f2b(v.x), f2b(v.y), f2b(v.z), f2b(v.w));
    }
    for (int idx = tid; idx < 64 * 8; idx += 256){
      int r = idx >> 3, c = idx & 7;
      *(ulonglong2*)&Ws[r][c * 8] = *(const ulonglong2*)(Wb + (long)(n0 + r) * Kpad + k0 + c * 8);
    }
    __syncthreads();
    bfrag a0 = *(const bfrag*)&As[w * 16 + col][quad * 8];
    bfrag a1 = *(const bfrag*)&As[w * 16 + col][32 + quad * 8];
    #pragma unroll
    for (int t = 0; t < 4; ++t){
      bfrag b0 = *(const bfrag*)&Ws[t * 16 + col][quad * 8];
      bfrag b1 = *(const bfrag*)&Ws[t * 16 + col][32 + quad * 8];
      acc[t] = __builtin_amdgcn_mfma_f32_16x16x32_bf16(a0, b0, acc[t], 0, 0, 0);
      acc[t] = __builtin_amdgcn_mfma_f32_16x16x32_bf16(a1, b1, acc[t], 0, 0, 0);
    }
    __syncthreads();
  }

  #pragma unroll
  for (int t = 0; t < 4; ++t){
    int n = n0 + t * 16 + col;
    if (n >= Nout) continue;
    float bv = bias[n];
    #pragma unroll
    for (int r = 0; r < 4; ++r){
      int row = m0 + w * 16 + quad * 4 + r;
      if (row >= M) continue;
      float v;
      if (ACT == 2){
        float bf = (offsets[row + 1] > offsets[row]) ? 1.f : 0.f;
        v = acc[t][r] + bf * bv;
        v = (v > 0.f) ? v : (__expf(v) - 1.f);
      } else {
        v = acc[t][r] + bv;
        if (ACT == 1) v = lrelu(v);
      }
      C[(long)row * Nout + n] = v;
    }
  }
}

// ---------------- MFMA edge kernel: he1 (bf16 out) + fused logits + exp + denom + deg ----------------
// block = 256 threads (4 waves), 64 edges. B-frags loaded DIRECTLY from global (Wbg L2-resident).
// LDS: Xs[64][72] unioned with he1s[64][216] (Xs dead after A-frag load).
#define HSTR 216
__global__ __launch_bounds__(256) void edge_mfma_kernel(
    const float* __restrict__ nf, const float* __restrict__ ef,
    const int* __restrict__ src, const int* __restrict__ dst,
    const u16* __restrict__ Wbg, const float* __restrict__ be1,
    const float* __restrict__ We2, const float* __restrict__ be2,
    const float* __restrict__ l1,
    u16* __restrict__ he1g, float* __restrict__ lex,
    int* __restrict__ deg, float* __restrict__ denom, int E)
{
  __shared__ __align__(16) u16 shm[64 * HSTR];  // Xs view: [64][72]; he1s view: [64][216]
  __shared__ float bias_s[208];
  __shared__ float w2hi_s[208];
  __shared__ float plds[64];
  __shared__ int srcs[64], dsts[64];

  int tid = threadIdx.x;
  long e0 = (long)blockIdx.x * 64;

  if (tid < 64){
    long e = e0 + tid;
    srcs[tid] = (e < E) ? src[e] : 0;
    dsts[tid] = (e < E) ? dst[e] : 0;
  }
  if (tid < 208){
    bias_s[tid] = (tid < G) ? be1[tid] : 0.f;
    w2hi_s[tid] = (tid < G) ? We2[G + tid] : 0.f;
  }
  __syncthreads();  // srcs ready
  // X fill: nf part as float4 (64 edges x 8 float4)
  for (int idx = tid; idx < 64 * 8; idx += 256){
    int el = idx >> 3, c = idx & 7;
    long e = e0 + el;
    float4 v = make_float4(0.f,0.f,0.f,0.f);
    if (e < E) v = *(const float4*)(nf + (long)srcs[el] * NDIM + c * 4);
    *(ushort4*)&shm[el * 72 + c * 4] = make_ushort4(f2b(v.x), f2b(v.y), f2b(v.z), f2b(v.w));
  }
  // ef part: 64*19 contiguous floats starting at e0*19 (coalesced)
  for (int idx = tid; idx < 64 * EDIM; idx += 256){
    long pos = e0 * EDIM + idx;
    float v = (pos < (long)E * EDIM) ? ef[pos] : 0.f;
    int el = idx / EDIM, k = idx - el * EDIM;
    shm[el * 72 + NDIM + k] = f2b(v);
  }
  // zero k in [51,64)
  for (int idx = tid; idx < 64 * 13; idx += 256){
    int el = idx / 13, k = 51 + (idx - el * 13);
    shm[el * 72 + k] = 0;
  }
  __syncthreads();

  int l = tid & 63, w = tid >> 6;
  int quad = l >> 4, col = l & 15;
  int m0 = w * 16;

  bfrag a0 = *(const bfrag*)&shm[(m0 + col) * 72 + quad * 8];
  bfrag a1 = *(const bfrag*)&shm[(m0 + col) * 72 + 32 + quad * 8];
  __syncthreads();  // all A-frags loaded; Xs region reusable as he1s

  ffrag acc[13];
  #pragma unroll
  for (int t = 0; t < 13; ++t){ acc[t].x = 0.f; acc[t].y = 0.f; acc[t].z = 0.f; acc[t].w = 0.f; }
  #pragma unroll
  for (int t = 0; t < 13; ++t){
    bfrag b0 = *(const bfrag*)(Wbg + (t * 16 + col) * 64 + quad * 8);
    bfrag b1 = *(const bfrag*)(Wbg + (t * 16 + col) * 64 + 32 + quad * 8);
    acc[t] = __builtin_amdgcn_mfma_f32_16x16x32_bf16(a0, b0, acc[t], 0, 0, 0);
    acc[t] = __builtin_amdgcn_mfma_f32_16x16x32_bf16(a1, b1, acc[t], 0, 0, 0);
  }

  // epilogue: bias + lrelu -> he1s staging, fused logit partial
  float pl[4] = {0.f, 0.f, 0.f, 0.f};
  #pragma unroll
  for (int t = 0; t < 13; ++t){
    int g = t * 16 + col;  // [0,208); cols >= 200 are zero-weight junk
    float bv = bias_s[g], wv = w2hi_s[g];
    #pragma unroll
    for (int r = 0; r < 4; ++r){
      int el = m0 + quad * 4 + r;
      float v = acc[t][r] + bv;
      v = lrelu(v);
      pl[r] += wv * v;
      shm[el * HSTR + g] = f2b(v);
    }
  }
  #pragma unroll
  for (int r = 0; r < 4; ++r){
    pl[r] += __shfl_xor(pl[r], 1, 16);
    pl[r] += __shfl_xor(pl[r], 2, 16);
    pl[r] += __shfl_xor(pl[r], 4, 16);
    pl[r] += __shfl_xor(pl[r], 8, 16);
  }
  if (col == 0){
    #pragma unroll
    for (int r = 0; r < 4; ++r) plds[m0 + quad * 4 + r] = pl[r];
  }
  __syncthreads();
  // coalesced he1 copy-out: 64 edges x 25 ushort8 chunks
  for (int idx = tid; idx < 1600; idx += 256){
    int el = idx / 25, c = idx - el * 25;
    long e = e0 + el;
    if (e < E)
      *(ulonglong2*)(he1g + e * G + c * 8) = *(const ulonglong2*)&shm[el * HSTR + c * 8];
  }
  if (tid < 64){
    long e = e0 + tid;
    if (e < E){
      int d = dsts[tid];
      float lg = lrelu(plds[tid] + l1[d] + be2[0]);
      float ex = __expf(lg);
      lex[e] = ex;
      atomicAdd(&denom[d], ex);
      atomicAdd(&deg[d], 1);
    }
  }
}

// ---------------- single-block exclusive scan (CSR offsets) ----------------
__global__ __launch_bounds__(1024) void scan_kernel(const int* __restrict__ deg, int* __restrict__ offs,
                                                    int* __restrict__ cur, int N){
  __shared__ int wsums[16];
  __shared__ int carry_s;
  int tid = threadIdx.x;
  int lane = tid & 63, wid = tid >> 6;
  if (tid == 0) carry_s = 0;
  __syncthreads();
  for (int base = 0; base < N; base += 1024){
    int i = base + tid;
    int v = (i < N) ? deg[i] : 0;
    int x = v;
    #pragma unroll
    for (int off = 1; off < 64; off <<= 1){
      int y = __shfl_up(x, off, 64);
      if (lane >= off) x += y;
    }
    if (lane == 63) wsums[wid] = x;
    __syncthreads();
    if (wid == 0){
      int w = (lane < 16) ? wsums[lane] : 0;
      #pragma unroll
      for (int off = 1; off < 16; off <<= 1){
        int y = __shfl_up(w, off, 64);
        if (lane >= off) w += y;
      }
      if (lane < 16) wsums[lane] = w;
    }
    __syncthreads();
    int wexcl = (wid == 0) ? 0 : wsums[wid - 1];
    int incl = carry_s + wexcl + x;
    if (i < N){ offs[i] = incl - v; cur[i] = incl - v; }
    __syncthreads();
    if (tid == 1023) carry_s = incl;
    __syncthreads();
  }
  if (threadIdx.x == 0) offs[N] = carry_s;
}

// ---------------- scatter (CSR edge ids) ----------------
__global__ void scatter_kernel(const int* __restrict__ dst, int* __restrict__ cur,
                               int* __restrict__ eids, int E){
  int e = blockIdx.x * 256 + threadIdx.x;
  if (e < E){
    int pos = atomicAdd(&cur[dst[e]], 1);
    eids[pos] = e;
  }
}

// ---------------- CSR weighted segment-sum: s[n] = (1/denom) * sum ex_e * he1[e] ----------------
__global__ __launch_bounds__(64) void segsum_kernel(const u16* __restrict__ he1, const float* __restrict__ ex,
    const float* __restrict__ denom, const int* __restrict__ offs, const int* __restrict__ eids,
    float* __restrict__ s, int N)
{
  int n = blockIdx.x;
  if (n >= N) return;
  int l = threadIdx.x;
  if (l >= 50) return;  // 50 lanes x 4 floats = 200
  int beg = offs[n], end = offs[n+1];
  float a0 = 0.f, a1 = 0.f, a2 = 0.f, a3 = 0.f;
  int j = beg;
  for (; j + 1 < end; j += 2){
    int ea = eids[j], eb = eids[j + 1];
    float wa = ex[ea], wb = ex[eb];
    ushort4 ha = *(const ushort4*)(he1 + (long)ea * G + l * 4);
    ushort4 hb = *(const ushort4*)(he1 + (long)eb * G + l * 4);
    a0 += wa * b2f(ha.x) + wb * b2f(hb.x);
    a1 += wa * b2f(ha.y) + wb * b2f(hb.y);
    a2 += wa * b2f(ha.z) + wb * b2f(hb.z);
    a3 += wa * b2f(ha.w) + wb * b2f(hb.w);
  }
  if (j < end){
    int ea = eids[j];
    float wa = ex[ea];
    ushort4 ha = *(const ushort4*)(he1 + (long)ea * G + l * 4);
    a0 += wa * b2f(ha.x); a1 += wa * b2f(ha.y); a2 += wa * b2f(ha.z); a3 += wa * b2f(ha.w);
  }
  float inv = (end > beg) ? 1.0f / denom[n] : 0.f;
  float4 o = make_float4(a0*inv, a1*inv, a2*inv, a3*inv);
  *(float4*)(s + (long)n * G + l * 4) = o;
}

// ---------------- fused GRU: gi = ctx@W_ih^T+b_ih, gh = hv@W_hh^T+b_hh, out = relu(GRU) ----------------
// block = 256 (4 waves), tile 64 rows x 64 cols, 6 accumulators (3 gates x {I,H}).
// W-frags loaded directly from global (Wihb/Whhb L2-resident, padded [768][256]).
__global__ __launch_bounds__(256) void gruf_kernel(
    const float* __restrict__ ctx, const float* __restrict__ hv,
    const u16* __restrict__ Wihb, const u16* __restrict__ Whhb,
    const float* __restrict__ b_ih, const float* __restrict__ b_hh,
    float* __restrict__ out, int M)
{
  __shared__ __align__(16) u16 Cs[64][72];
  __shared__ __align__(16) u16 Hs[64][72];
  int tid = threadIdx.x;
  int m0 = blockIdx.y * 64, g0 = blockIdx.x * 64;
  int l = tid & 63, w = tid >> 6, quad = l >> 4, col = l & 15;

  ffrag aI[3][4], aH[3][4];
  #pragma unroll
  for (int gt = 0; gt < 3; ++gt)
    #pragma unroll
    for (int t = 0; t < 4; ++t){
      aI[gt][t].x = 0.f; aI[gt][t].y = 0.f; aI[gt][t].z = 0.f; aI[gt][t].w = 0.f;
      aH[gt][t].x = 0.f; aH[gt][t].y = 0.f; aH[gt][t].z = 0.f; aH[gt][t].w = 0.f;
    }

  for (int kc = 0; kc < 4; ++kc){
    int k0 = kc << 6;
    for (int idx = tid; idx < 64 * 16; idx += 256){
      int r = idx >> 4, c4 = idx & 15;
      int row = m0 + r, k = k0 + c4 * 4;
      float4 cv = make_float4(0.f,0.f,0.f,0.f), hvv = make_float4(0.f,0.f,0.f,0.f);
      if (row < M && k < G){
        cv  = *(const float4*)(ctx + (long)row * G + k);
        hvv = *(const float4*)(hv  + (long)row * G + k);
      }
      *(ushort4*)&Cs[r][c4 * 4] = make_ushort4(f2b(cv.x), f2b(cv.y), f2b(cv.z), f2b(cv.w));
      *(ushort4*)&Hs[r][c4 * 4] = make_ushort4(f2b(hvv.x), f2b(hvv.y), f2b(hvv.z), f2b(hvv.w));
    }
    __syncthreads();
    bfrag ca0 = *(const bfrag*)&Cs[w * 16 + col][quad * 8];
    bfrag ca1 = *(const bfrag*)&Cs[w * 16 + col][32 + quad * 8];
    bfrag ha0 = *(const bfrag*)&Hs[w * 16 + col][quad * 8];
    bfrag ha1 = *(const bfrag*)&Hs[w * 16 + col][32 + quad * 8];
    #pragma unroll
    for (int gt = 0; gt < 3; ++gt){
      #pragma unroll
      for (int t = 0; t < 4; ++t){
        long wr = (long)(gt * G + g0 + t * 16 + col) * 256 + k0 + quad * 8;
        bfrag bi0 = *(const bfrag*)(Wihb + wr);
        bfrag bi1 = *(const bfrag*)(Wihb + wr + 32);
        bfrag bh0 = *(const bfrag*)(Whhb + wr);
        bfrag bh1 = *(const bfrag*)(Whhb + wr + 32);
        aI[gt][t] = __builtin_amdgcn_mfma_f32_16x16x32_bf16(ca0, bi0, aI[gt][t], 0, 0, 0);
        aI[gt][t] = __builtin_amdgcn_mfma_f32_16x16x32_bf16(ca1, bi1, aI[gt][t], 0, 0, 0);
        aH[gt][t] = __builtin_amdgcn_mfma_f32_16x16x32_bf16(ha0, bh0, aH[gt][t], 0, 0, 0);
        aH[gt][t] = __builtin_amdgcn_mfma_f32_16x16x32_bf16(ha1, bh1, aH[gt][t], 0, 0, 0);
      }
    }
    __syncthreads();
  }

  #pragma unroll
  for (int t = 0; t < 4; ++t){
    int n = g0 + t * 16 + col;
    if (n >= G) continue;
    float bir = b_ih[n], biz = b_ih[G + n], bin = b_ih[2 * G + n];
    float bhr = b_hh[n], bhz = b_hh[G + n], bhn = b_hh[2 * G + n];
    #pragma unroll
    for (int r = 0; r < 4; ++r){
      int row = m0 + w * 16 + quad * 4 + r;
      if (row >= M) continue;
      float ir = aI[0][t][r] + bir, iz = aI[1][t][r] + biz, inn = aI[2][t][r] + bin;
      float hr = aH[0][t][r] + bhr, hz = aH[1][t][r] + bhz, hn = aH[2][t][r] + bhn;
      float rg = 1.f / (1.f + __expf(-(ir + hr)));
      float zg = 1.f / (1.f + __expf(-(iz + hz)));
      float ng = tanhf(inn + rg * hn);
      float hvv = hv[(long)row * G + n];
      float h = (1.f - zg) * ng + zg * hvv;
      out[(long)row * G + n] = h > 0.f ? h : 0.f;
    }
  }
}

extern "C" void kernel_launch(void* const* d_in, const int* in_sizes, int n_in,
                              void* d_out, int out_size, void* d_ws, size_t ws_size,
                              hipStream_t stream)
{
  const float* nf   = (const float*)d_in[0];
  const float* ef   = (const float*)d_in[1];
  const int*   src  = (const int*)d_in[2];
  const int*   dst  = (const int*)d_in[3];
  const float* Wn   = (const float*)d_in[4];
  const float* bn   = (const float*)d_in[5];
  const float* We1  = (const float*)d_in[6];
  const float* be1  = (const float*)d_in[7];
  const float* We2  = (const float*)d_in[8];
  const float* be2  = (const float*)d_in[9];
  const float* Wet  = (const float*)d_in[10];
  const float* bet  = (const float*)d_in[11];
  const float* W_ih = (const float*)d_in[12];
  const float* b_ih = (const float*)d_in[13];
  const float* W_hh = (const float*)d_in[14];
  const float* b_hh = (const float*)d_in[15];
  int N = in_sizes[0] / NDIM;   // 25000
  int E = in_sizes[2];          // 500000
  float* out = (float*)d_out;

  char* p = (char*)d_ws;
  auto alloc = [&](size_t b){ char* r = p; p += (b + 255) & ~(size_t)255; return r; };
  float* hv    = (float*)alloc((size_t)N * G * 4);       // 20 MB
  float* s     = (float*)alloc((size_t)N * G * 4);       // 20 MB
  float* lex   = (float*)alloc((size_t)E * 4);           // ex
  float* denom = (float*)alloc((size_t)N * 4);
  int*   deg   = (int*)  alloc((size_t)N * 4);
  int*   offs  = (int*)  alloc((size_t)(N + 1) * 4);
  int*   cur   = (int*)  alloc((size_t)N * 4);
  int*   eids  = (int*)  alloc((size_t)E * 4);
  u16*   Wbg   = (u16*)  alloc((size_t)208 * 64 * 2);    // We1 bf16 padded
  float* l1    = (float*)alloc((size_t)N * 4);
  u16*   Wnb   = (u16*)  alloc((size_t)256 * 64 * 2);
  u16*   Wetb  = (u16*)  alloc((size_t)256 * 256 * 2);
  u16*   Wihb  = (u16*)  alloc((size_t)768 * 256 * 2);
  u16*   Whhb  = (u16*)  alloc((size_t)768 * 256 * 2);
  char*  big   = alloc((size_t)E * G * 2);               // 200 MB: he1 (bf16), later context
  u16*   he1   = (u16*)big;
  float* ctx   = (float*)big;                            // after he1 is dead

  int eb = (E + 255) / 256;
  int mb = (N + 63) / 64;

  init_kernel<<<dim3((N + 255) / 256), dim3(256), 0, stream>>>(denom, deg, N);
  prep_w_kernel<<<dim3((208 * 64 + 255) / 256), dim3(256), 0, stream>>>(We1, Wbg, G, KIN, 208, 64);
  prep_w_kernel<<<dim3((256 * 64 + 255) / 256), dim3(256), 0, stream>>>(Wn, Wnb, G, NDIM, 256, 64);
  prep_w_kernel<<<dim3((256 * 256 + 255) / 256), dim3(256), 0, stream>>>(Wet, Wetb, G, G, 256, 256);
  prep_w_kernel<<<dim3((768 * 256 + 255) / 256), dim3(256), 0, stream>>>(W_ih, Wihb, 3 * G, G, 768, 256);
  prep_w_kernel<<<dim3((768 * 256 + 255) / 256), dim3(256), 0, stream>>>(W_hh, Whhb, 3 * G, G, 768, 256);

  // hv = lrelu(nf @ Wn^T + bn)
  mgemm_kernel<1><<<dim3(4, mb), dim3(256), 0, stream>>>(nf, Wnb, bn, nullptr, hv, N, NDIM, G, 64);
  l1_kernel<<<dim3((N * 64 + 255) / 256), dim3(256), 0, stream>>>(hv, We2, l1, N);
  edge_mfma_kernel<<<dim3((E + 63) / 64), dim3(256), 0, stream>>>(nf, ef, src, dst, Wbg, be1, We2, be2, l1, he1, lex, deg, denom, E);
  scan_kernel<<<dim3(1), dim3(1024), 0, stream>>>(deg, offs, cur, N);
  scatter_kernel<<<dim3(eb), dim3(256), 0, stream>>>(dst, cur, eids, E);
  segsum_kernel<<<dim3(N), dim3(64), 0, stream>>>(he1, lex, denom, offs, eids, s, N);
  // context = elu(s @ Wet^T + bet[nonempty])  (he1 dead now; ctx aliases big)
  mgemm_kernel<2><<<dim3(4, mb), dim3(256), 0, stream>>>(s, Wetb, bet, offs, ctx, N, G, G, 256);
  gruf_kernel<<<dim3(4, mb), dim3(256), 0, stream>>>(ctx, hv, Wihb, Whhb, b_ih, b_hh, out, N);
}

// Round 5
// 562.113 us; speedup vs baseline: 2.6014x; 1.1939x over previous
//
#include <hip/hip_runtime.h>
#include <hip/hip_bf16.h>

#define G 200
#define NDIM 32
#define EDIM 19
#define KIN 51  // NDIM + EDIM

typedef unsigned short u16;
typedef unsigned int u32;

typedef __attribute__((ext_vector_type(8))) short bfrag;   // 8 bf16 (4 VGPRs)
typedef __attribute__((ext_vector_type(4))) float ffrag;   // 4 fp32 acc

__device__ __forceinline__ float lrelu(float x){ return x > 0.f ? x : 0.01f*x; }
// bf16 pack (RNE) / unpack
__device__ __forceinline__ u16 f2b(float x){ u32 u = __float_as_uint(x); return (u16)((u + 0x7fffu + ((u >> 16) & 1u)) >> 16); }
__device__ __forceinline__ float b2f(u16 x){ return __uint_as_float(((u32)x) << 16); }

// ---------------- init ----------------
__global__ void init_kernel(float* __restrict__ denom, int* __restrict__ deg, int N){
  int i = blockIdx.x * 256 + threadIdx.x;
  if (i < N){ denom[i] = 0.f; deg[i] = 0; }
}

// ---------------- generic weight prep: W [Nr][Kc] fp32 -> Wb [Npad][Kpad] bf16 ----------------
__global__ void prep_w_kernel(const float* __restrict__ W, u16* __restrict__ Wb,
                              int Nr, int Kc, int Npad, int Kpad){
  int idx = blockIdx.x * 256 + threadIdx.x;
  if (idx < Npad * Kpad){
    int r = idx / Kpad, k = idx % Kpad;
    float v = (r < Nr && k < Kc) ? W[r * Kc + k] : 0.f;
    Wb[idx] = f2b(v);
  }
}

// ---------------- degree histogram (dst only) ----------------
__global__ void deghist_kernel(const int* __restrict__ dst, int* __restrict__ deg, int E){
  int e = blockIdx.x * 256 + threadIdx.x;
  if (e < E) atomicAdd(&deg[dst[e]], 1);
}

// ---------------- l1[n] = dot(We2[0:200], hv[n]) ----------------
__global__ __launch_bounds__(256) void l1_kernel(const float* __restrict__ hv, const float* __restrict__ We2,
                                                 float* __restrict__ l1, int N){
  int wv = (blockIdx.x * 256 + threadIdx.x) >> 6;
  int lane = threadIdx.x & 63;
  if (wv >= N) return;
  float p = 0.f;
  for (int g = lane; g < G; g += 64) p += We2[g] * hv[(long)wv * G + g];
  #pragma unroll
  for (int off = 32; off; off >>= 1) p += __shfl_down(p, off, 64);
  if (lane == 0) l1[wv] = p;
}

// ---------------- MFMA node GEMM: C = act(A[M,K] @ W^T + bias), W pre-padded bf16 [Npad][Kpad] ----------------
// ACT: 0 = none, 1 = leaky_relu, 2 = elu with per-row bias flag (offsets[row+1]>offsets[row])
template<int ACT>
__global__ __launch_bounds__(256) void mgemm_kernel(
    const float* __restrict__ A, const u16* __restrict__ Wb, const float* __restrict__ bias,
    const int* __restrict__ offsets, float* __restrict__ C, int M, int K, int Nout, int Kpad)
{
  __shared__ __align__(16) u16 As[64][72];
  __shared__ __align__(16) u16 Ws[64][72];
  int tid = threadIdx.x;
  int m0 = blockIdx.y * 64, n0 = blockIdx.x * 64;
  int l = tid & 63, w = tid >> 6, quad = l >> 4, col = l & 15;

  ffrag acc[4];
  #pragma unroll
  for (int t = 0; t < 4; ++t){ acc[t].x = 0.f; acc[t].y = 0.f; acc[t].z = 0.f; acc[t].w = 0.f; }

  int nK = Kpad >> 6;
  for (int kc = 0; kc < nK; ++kc){
    int k0 = kc << 6;
    for (int idx = tid; idx < 64 * 16; idx += 256){
      int r = idx >> 4, c4 = idx & 15;
      int row = m0 + r, k = k0 + c4 * 4;
      float4 v = make_float4(0.f,0.f,0.f,0.f);
      if (row < M && k < K) v = *(const float4*)(A + (long)row * K + k);
      *(ushort4*)&As[r][c4 * 4] = make_ushort4(f2b(v.x), f2b(v.y), f2b(v.z), f2b(v.w));
    }
    for (int idx = tid; idx < 64 * 8; idx += 256){
      int r = idx >> 3, c = idx & 7;
      *(ulonglong2*)&Ws[r][c * 8] = *(const ulonglong2*)(Wb + (long)(n0 + r) * Kpad + k0 + c * 8);
    }
    __syncthreads();
    bfrag a0 = *(const bfrag*)&As[w * 16 + col][quad * 8];
    bfrag a1 = *(const bfrag*)&As[w * 16 + col][32 + quad * 8];
    #pragma unroll
    for (int t = 0; t < 4; ++t){
      bfrag b0 = *(const bfrag*)&Ws[t * 16 + col][quad * 8];
      bfrag b1 = *(const bfrag*)&Ws[t * 16 + col][32 + quad * 8];
      acc[t] = __builtin_amdgcn_mfma_f32_16x16x32_bf16(a0, b0, acc[t], 0, 0, 0);
      acc[t] = __builtin_amdgcn_mfma_f32_16x16x32_bf16(a1, b1, acc[t], 0, 0, 0);
    }
    __syncthreads();
  }

  #pragma unroll
  for (int t = 0; t < 4; ++t){
    int n = n0 + t * 16 + col;
    if (n >= Nout) continue;
    float bv = bias[n];
    #pragma unroll
    for (int r = 0; r < 4; ++r){
      int row = m0 + w * 16 + quad * 4 + r;
      if (row >= M) continue;
      float v;
      if (ACT == 2){
        float bf = (offsets[row + 1] > offsets[row]) ? 1.f : 0.f;
        v = acc[t][r] + bf * bv;
        v = (v > 0.f) ? v : (__expf(v) - 1.f);
      } else {
        v = acc[t][r] + bv;
        if (ACT == 1) v = lrelu(v);
      }
      C[(long)row * Nout + n] = v;
    }
  }
}

// ---------------- MFMA edge kernel: he1 -> CSR slots (bf16) + logits + exp + denom ----------------
// block = 256 threads (4 waves), 64 edges. B-frags loaded DIRECTLY from global (Wbg L2-resident).
// LDS: Xs[64][72] unioned with he1s[64][216]. Each edge writes he1/ex at its CSR position
// pos = atomicAdd(cur[dst]) so segsum reads are sequential and no eids array is needed.
#define HSTR 216
__global__ __launch_bounds__(256) void edge_mfma_kernel(
    const float* __restrict__ nf, const float* __restrict__ ef,
    const int* __restrict__ src, const int* __restrict__ dst,
    const u16* __restrict__ Wbg, const float* __restrict__ be1,
    const float* __restrict__ We2, const float* __restrict__ be2,
    const float* __restrict__ l1, int* __restrict__ cur,
    u16* __restrict__ he1g, float* __restrict__ lex,
    float* __restrict__ denom, int E)
{
  __shared__ __align__(16) u16 shm[64 * HSTR];  // Xs view: [64][72]; he1s view: [64][216]
  __shared__ float bias_s[208];
  __shared__ float w2hi_s[208];
  __shared__ float plds[64];
  __shared__ int srcs[64], dsts[64], poss[64];

  int tid = threadIdx.x;
  long e0 = (long)blockIdx.x * 64;

  if (tid < 64){
    long e = e0 + tid;
    srcs[tid] = (e < E) ? src[e] : 0;
    dsts[tid] = (e < E) ? dst[e] : 0;
  }
  if (tid < 208){
    bias_s[tid] = (tid < G) ? be1[tid] : 0.f;
    w2hi_s[tid] = (tid < G) ? We2[G + tid] : 0.f;
  }
  __syncthreads();  // srcs ready
  // X fill: nf part as float4 (64 edges x 8 float4)
  for (int idx = tid; idx < 64 * 8; idx += 256){
    int el = idx >> 3, c = idx & 7;
    long e = e0 + el;
    float4 v = make_float4(0.f,0.f,0.f,0.f);
    if (e < E) v = *(const float4*)(nf + (long)srcs[el] * NDIM + c * 4);
    *(ushort4*)&shm[el * 72 + c * 4] = make_ushort4(f2b(v.x), f2b(v.y), f2b(v.z), f2b(v.w));
  }
  // ef part: 64*19 contiguous floats starting at e0*19 (coalesced)
  for (int idx = tid; idx < 64 * EDIM; idx += 256){
    long pos = e0 * EDIM + idx;
    float v = (pos < (long)E * EDIM) ? ef[pos] : 0.f;
    int el = idx / EDIM, k = idx - el * EDIM;
    shm[el * 72 + NDIM + k] = f2b(v);
  }
  // zero k in [51,64)
  for (int idx = tid; idx < 64 * 13; idx += 256){
    int el = idx / 13, k = 51 + (idx - el * 13);
    shm[el * 72 + k] = 0;
  }
  __syncthreads();

  int l = tid & 63, w = tid >> 6;
  int quad = l >> 4, col = l & 15;
  int m0 = w * 16;

  bfrag a0 = *(const bfrag*)&shm[(m0 + col) * 72 + quad * 8];
  bfrag a1 = *(const bfrag*)&shm[(m0 + col) * 72 + 32 + quad * 8];
  __syncthreads();  // all A-frags loaded; Xs region reusable as he1s

  ffrag acc[13];
  #pragma unroll
  for (int t = 0; t < 13; ++t){ acc[t].x = 0.f; acc[t].y = 0.f; acc[t].z = 0.f; acc[t].w = 0.f; }
  #pragma unroll
  for (int t = 0; t < 13; ++t){
    bfrag b0 = *(const bfrag*)(Wbg + (t * 16 + col) * 64 + quad * 8);
    bfrag b1 = *(const bfrag*)(Wbg + (t * 16 + col) * 64 + 32 + quad * 8);
    acc[t] = __builtin_amdgcn_mfma_f32_16x16x32_bf16(a0, b0, acc[t], 0, 0, 0);
    acc[t] = __builtin_amdgcn_mfma_f32_16x16x32_bf16(a1, b1, acc[t], 0, 0, 0);
  }

  // epilogue: bias + lrelu -> he1s staging, fused logit partial
  float pl[4] = {0.f, 0.f, 0.f, 0.f};
  #pragma unroll
  for (int t = 0; t < 13; ++t){
    int g = t * 16 + col;  // [0,208); cols >= 200 are zero-weight junk
    float bv = bias_s[g], wv = w2hi_s[g];
    #pragma unroll
    for (int r = 0; r < 4; ++r){
      int el = m0 + quad * 4 + r;
      float v = acc[t][r] + bv;
      v = lrelu(v);
      pl[r] += wv * v;
      shm[el * HSTR + g] = f2b(v);
    }
  }
  #pragma unroll
  for (int r = 0; r < 4; ++r){
    pl[r] += __shfl_xor(pl[r], 1, 16);
    pl[r] += __shfl_xor(pl[r], 2, 16);
    pl[r] += __shfl_xor(pl[r], 4, 16);
    pl[r] += __shfl_xor(pl[r], 8, 16);
  }
  if (col == 0){
    #pragma unroll
    for (int r = 0; r < 4; ++r) plds[m0 + quad * 4 + r] = pl[r];
  }
  __syncthreads();
  // per-edge tail: CSR slot, logit -> exp, denom
  if (tid < 64){
    long e = e0 + tid;
    if (e < E){
      int d = dsts[tid];
      int pos = atomicAdd(&cur[d], 1);
      poss[tid] = pos;
      float lg = lrelu(plds[tid] + l1[d] + be2[0]);
      float ex = __expf(lg);
      lex[pos] = ex;
      atomicAdd(&denom[d], ex);
    }
  }
  __syncthreads();  // poss visible
  // he1 copy-out to CSR rows: 64 edges x 25 ushort8 chunks
  for (int idx = tid; idx < 1600; idx += 256){
    int el = idx / 25, c = idx - el * 25;
    long e = e0 + el;
    if (e < E)
      *(ulonglong2*)(he1g + (long)poss[el] * G + c * 8) = *(const ulonglong2*)&shm[el * HSTR + c * 8];
  }
}

// ---------------- single-block exclusive scan (CSR offsets) ----------------
__global__ __launch_bounds__(1024) void scan_kernel(const int* __restrict__ deg, int* __restrict__ offs,
                                                    int* __restrict__ cur, int N){
  __shared__ int wsums[16];
  __shared__ int carry_s;
  int tid = threadIdx.x;
  int lane = tid & 63, wid = tid >> 6;
  if (tid == 0) carry_s = 0;
  __syncthreads();
  for (int base = 0; base < N; base += 1024){
    int i = base + tid;
    int v = (i < N) ? deg[i] : 0;
    int x = v;
    #pragma unroll
    for (int off = 1; off < 64; off <<= 1){
      int y = __shfl_up(x, off, 64);
      if (lane >= off) x += y;
    }
    if (lane == 63) wsums[wid] = x;
    __syncthreads();
    if (wid == 0){
      int w = (lane < 16) ? wsums[lane] : 0;
      #pragma unroll
      for (int off = 1; off < 16; off <<= 1){
        int y = __shfl_up(w, off, 64);
        if (lane >= off) w += y;
      }
      if (lane < 16) wsums[lane] = w;
    }
    __syncthreads();
    int wexcl = (wid == 0) ? 0 : wsums[wid - 1];
    int incl = carry_s + wexcl + x;
    if (i < N){ offs[i] = incl - v; cur[i] = incl - v; }
    __syncthreads();
    if (tid == 1023) carry_s = incl;
    __syncthreads();
  }
  if (threadIdx.x == 0) offs[N] = carry_s;
}

// ---------------- CSR weighted segment-sum (sequential rows, no eids) ----------------
// wave per node, 4 nodes per block. s[n] = (1/denom) * sum_j lex[j] * he1[j]
__global__ __launch_bounds__(256) void segsum_kernel(const u16* __restrict__ he1, const float* __restrict__ lex,
    const float* __restrict__ denom, const int* __restrict__ offs, float* __restrict__ s, int N)
{
  int n = blockIdx.x * 4 + (threadIdx.x >> 6);
  if (n >= N) return;
  int l = threadIdx.x & 63;
  if (l >= 50) return;  // 50 lanes x 4 floats = 200
  int beg = offs[n], end = offs[n+1];
  float a0 = 0.f, a1 = 0.f, a2 = 0.f, a3 = 0.f;
  int j = beg;
  for (; j + 1 < end; j += 2){
    float wa = lex[j], wb = lex[j + 1];
    ushort4 ha = *(const ushort4*)(he1 + (long)j * G + l * 4);
    ushort4 hb = *(const ushort4*)(he1 + (long)(j + 1) * G + l * 4);
    a0 += wa * b2f(ha.x) + wb * b2f(hb.x);
    a1 += wa * b2f(ha.y) + wb * b2f(hb.y);
    a2 += wa * b2f(ha.z) + wb * b2f(hb.z);
    a3 += wa * b2f(ha.w) + wb * b2f(hb.w);
  }
  if (j < end){
    float wa = lex[j];
    ushort4 ha = *(const ushort4*)(he1 + (long)j * G + l * 4);
    a0 += wa * b2f(ha.x); a1 += wa * b2f(ha.y); a2 += wa * b2f(ha.z); a3 += wa * b2f(ha.w);
  }
  float inv = (end > beg) ? 1.0f / denom[n] : 0.f;
  float4 o = make_float4(a0*inv, a1*inv, a2*inv, a3*inv);
  *(float4*)(s + (long)n * G + l * 4) = o;
}

// ---------------- GRU gates + relu ----------------
__device__ __forceinline__ float gruc(float ir, float iz, float inn, float hr, float hz, float hn, float hvv){
  float r = 1.f / (1.f + __expf(-(ir + hr)));
  float z = 1.f / (1.f + __expf(-(iz + hz)));
  float n = tanhf(inn + r * hn);
  float h = (1.f - z) * n + z * hvv;
  return h > 0.f ? h : 0.f;
}

__global__ void gru_kernel(const float* __restrict__ gi, const float* __restrict__ gh,
                           const float* __restrict__ hv, float* __restrict__ out, int N){
  int idx = blockIdx.x * 256 + threadIdx.x;
  if (idx >= N * 50) return;
  int i = idx / 50, g = (idx % 50) * 4;
  const float* gir = gi + (long)i * 600;
  const float* ghr = gh + (long)i * 600;
  float4 ir = *(const float4*)(gir + g);
  float4 iz = *(const float4*)(gir + 200 + g);
  float4 in_ = *(const float4*)(gir + 400 + g);
  float4 hr = *(const float4*)(ghr + g);
  float4 hz = *(const float4*)(ghr + 200 + g);
  float4 hn = *(const float4*)(ghr + 400 + g);
  float4 h = *(const float4*)(hv + (long)i * 200 + g);
  float4 o;
  o.x = gruc(ir.x, iz.x, in_.x, hr.x, hz.x, hn.x, h.x);
  o.y = gruc(ir.y, iz.y, in_.y, hr.y, hz.y, hn.y, h.y);
  o.z = gruc(ir.z, iz.z, in_.z, hr.z, hz.z, hn.z, h.z);
  o.w = gruc(ir.w, iz.w, in_.w, hr.w, hz.w, hn.w, h.w);
  *(float4*)(out + (long)i * 200 + g) = o;
}

extern "C" void kernel_launch(void* const* d_in, const int* in_sizes, int n_in,
                              void* d_out, int out_size, void* d_ws, size_t ws_size,
                              hipStream_t stream)
{
  const float* nf   = (const float*)d_in[0];
  const float* ef   = (const float*)d_in[1];
  const int*   src  = (const int*)d_in[2];
  const int*   dst  = (const int*)d_in[3];
  const float* Wn   = (const float*)d_in[4];
  const float* bn   = (const float*)d_in[5];
  const float* We1  = (const float*)d_in[6];
  const float* be1  = (const float*)d_in[7];
  const float* We2  = (const float*)d_in[8];
  const float* be2  = (const float*)d_in[9];
  const float* Wet  = (const float*)d_in[10];
  const float* bet  = (const float*)d_in[11];
  const float* W_ih = (const float*)d_in[12];
  const float* b_ih = (const float*)d_in[13];
  const float* W_hh = (const float*)d_in[14];
  const float* b_hh = (const float*)d_in[15];
  int N = in_sizes[0] / NDIM;   // 25000
  int E = in_sizes[2];          // 500000
  float* out = (float*)d_out;

  char* p = (char*)d_ws;
  auto alloc = [&](size_t b){ char* r = p; p += (b + 255) & ~(size_t)255; return r; };
  float* hv    = (float*)alloc((size_t)N * G * 4);       // 20 MB
  float* s     = (float*)alloc((size_t)N * G * 4);       // 20 MB
  float* lex   = (float*)alloc((size_t)E * 4);           // ex, CSR-ordered
  float* denom = (float*)alloc((size_t)N * 4);
  int*   deg   = (int*)  alloc((size_t)N * 4);
  int*   offs  = (int*)  alloc((size_t)(N + 1) * 4);
  int*   cur   = (int*)  alloc((size_t)N * 4);
  u16*   Wbg   = (u16*)  alloc((size_t)208 * 64 * 2);    // We1 bf16 padded
  float* l1    = (float*)alloc((size_t)N * 4);
  u16*   Wnb   = (u16*)  alloc((size_t)256 * 64 * 2);
  u16*   Wetb  = (u16*)  alloc((size_t)256 * 256 * 2);
  u16*   Wihb  = (u16*)  alloc((size_t)640 * 256 * 2);
  u16*   Whhb  = (u16*)  alloc((size_t)640 * 256 * 2);
  char*  big   = alloc((size_t)E * G * 2);               // 200 MB: he1 (bf16, CSR), later ctx/gi/gh
  u16*   he1   = (u16*)big;
  size_t NG4 = (size_t)N * G * 4;
  float* ctx   = (float*)big;                            // after he1 is dead
  float* gi    = (float*)(big + NG4);
  float* gh    = (float*)(big + NG4 + (size_t)N * 3 * G * 4);

  int eb = (E + 255) / 256;
  int mb = (N + 63) / 64;

  init_kernel<<<dim3((N + 255) / 256), dim3(256), 0, stream>>>(denom, deg, N);
  prep_w_kernel<<<dim3((208 * 64 + 255) / 256), dim3(256), 0, stream>>>(We1, Wbg, G, KIN, 208, 64);
  prep_w_kernel<<<dim3((256 * 64 + 255) / 256), dim3(256), 0, stream>>>(Wn, Wnb, G, NDIM, 256, 64);
  prep_w_kernel<<<dim3((256 * 256 + 255) / 256), dim3(256), 0, stream>>>(Wet, Wetb, G, G, 256, 256);
  prep_w_kernel<<<dim3((640 * 256 + 255) / 256), dim3(256), 0, stream>>>(W_ih, Wihb, 3 * G, G, 640, 256);
  prep_w_kernel<<<dim3((640 * 256 + 255) / 256), dim3(256), 0, stream>>>(W_hh, Whhb, 3 * G, G, 640, 256);
  deghist_kernel<<<dim3(eb), dim3(256), 0, stream>>>(dst, deg, E);
  scan_kernel<<<dim3(1), dim3(1024), 0, stream>>>(deg, offs, cur, N);

  // hv = lrelu(nf @ Wn^T + bn)
  mgemm_kernel<1><<<dim3(4, mb), dim3(256), 0, stream>>>(nf, Wnb, bn, nullptr, hv, N, NDIM, G, 64);
  l1_kernel<<<dim3((N * 64 + 255) / 256), dim3(256), 0, stream>>>(hv, We2, l1, N);
  edge_mfma_kernel<<<dim3((E + 63) / 64), dim3(256), 0, stream>>>(nf, ef, src, dst, Wbg, be1, We2, be2, l1, cur, he1, lex, denom, E);
  segsum_kernel<<<dim3((N + 3) / 4), dim3(256), 0, stream>>>(he1, lex, denom, offs, s, N);
  // context = elu(s @ Wet^T + bet[nonempty])  (he1 dead now)
  mgemm_kernel<2><<<dim3(4, mb), dim3(256), 0, stream>>>(s, Wetb, bet, offs, ctx, N, G, G, 256);
  mgemm_kernel<0><<<dim3(10, mb), dim3(256), 0, stream>>>(ctx, Wihb, b_ih, nullptr, gi, N, G, 3 * G, 256);
  mgemm_kernel<0><<<dim3(10, mb), dim3(256), 0, stream>>>(hv, Whhb, b_hh, nullptr, gh, N, G, 3 * G, 256);
  gru_kernel<<<dim3((N * 50 + 255) / 256), dim3(256), 0, stream>>>(gi, gh, hv, out, N);
}